// Round 1
// baseline (3098.629 us; speedup 1.0000x reference)
//
#include <hip/hip_runtime.h>

#define N_NODES 40000
#define E_EDGES 640000
#define FDIM 128
#define RREL 4
#define KTOT (RREL * FDIM + FDIM)  // 640

// ---------------------------------------------------------------------------
// Scatter: per edge e, acc[dst*R+rel][:] += x[src][:], cnt[dst*R+rel] += 1.
// 32 threads per edge (float4 each), 8 edges per 256-thread block.
// ---------------------------------------------------------------------------
__global__ __launch_bounds__(256) void scatter_kernel(
    const float* __restrict__ x,
    const int* __restrict__ src,
    const int* __restrict__ dst,
    const int* __restrict__ etype,
    float* __restrict__ acc,
    float* __restrict__ cnt) {
    int e = blockIdx.x * 8 + (threadIdx.x >> 5);
    if (e >= E_EDGES) return;
    int lane = threadIdx.x & 31;
    int s = src[e];
    int d = dst[e];
    int r = etype[e];
    int seg = d * RREL + r;
    const float4* xv = reinterpret_cast<const float4*>(x + (size_t)s * FDIM);
    float4 v = xv[lane];
    float* a = acc + (size_t)seg * FDIM + lane * 4;
    atomicAdd(a + 0, v.x);
    atomicAdd(a + 1, v.y);
    atomicAdd(a + 2, v.z);
    atomicAdd(a + 3, v.w);
    if (lane == 0) atomicAdd(cnt + seg, 1.0f);
}

// ---------------------------------------------------------------------------
// Fused GEMM: out[n,:] = ( [mean(n,0..3,:) | x(n,:)] ) @ [w ; root] + bias
// A is N x 640 (mean computed on the fly from acc/cnt), B is 640 x 128
// (w flattened [512x128] stacked on root [128x128]).
// BM=64 rows per block, full 128 cols, BK=32. 256 threads, each computes 4x8.
// ---------------------------------------------------------------------------
#define BM 64
#define BK 32

template <int RELU>
__global__ __launch_bounds__(256) void rgcn_gemm(
    const float* __restrict__ acc, const float* __restrict__ cnt,
    const float* __restrict__ xin, const float* __restrict__ w,
    const float* __restrict__ root, const float* __restrict__ bias,
    float* __restrict__ out) {
    __shared__ float sA[BM][BK + 1];     // [m][k], pad to kill write conflicts
    __shared__ float sB[BK][FDIM + 4];   // [k][o]
    __shared__ float sRcp[BM][RREL];

    const int row0 = blockIdx.x * BM;
    const int tid  = threadIdx.x;

    // one rcp-count per thread (64 rows x 4 relations = 256)
    {
        int m = tid >> 2;
        int r = tid & 3;
        float c = cnt[(size_t)(row0 + m) * RREL + r];
        sRcp[m][r] = 1.0f / fmaxf(c, 1.0f);
    }
    __syncthreads();

    const int ty = tid >> 4;   // 0..15 -> rows ty*4..ty*4+3
    const int tx = tid & 15;   // 0..15 -> cols tx*8..tx*8+7

    float c[4][8];
#pragma unroll
    for (int j = 0; j < 4; ++j)
#pragma unroll
        for (int i = 0; i < 8; ++i) c[j][i] = 0.0f;

    for (int kb = 0; kb < KTOT; kb += BK) {
        // load A tile 64x32: 8 elems/thread
#pragma unroll
        for (int i = 0; i < 8; ++i) {
            int id = tid + i * 256;
            int m  = id >> 5;
            int kk = id & 31;
            int k  = kb + kk;
            int n  = row0 + m;
            float v;
            if (k < RREL * FDIM) {
                v = acc[(size_t)n * (RREL * FDIM) + k] * sRcp[m][k >> 7];
            } else {
                v = xin[(size_t)n * FDIM + (k - RREL * FDIM)];
            }
            sA[m][kk] = v;
        }
        // load B tile 32x128: 16 elems/thread
#pragma unroll
        for (int i = 0; i < 16; ++i) {
            int id = tid + i * 256;
            int kk = id >> 7;
            int o  = id & 127;
            int k  = kb + kk;
            float v;
            if (k < RREL * FDIM) v = w[(size_t)k * FDIM + o];
            else                 v = root[(size_t)(k - RREL * FDIM) * FDIM + o];
            sB[kk][o] = v;
        }
        __syncthreads();

#pragma unroll
        for (int kk = 0; kk < BK; ++kk) {
            float a[4], b[8];
#pragma unroll
            for (int j = 0; j < 4; ++j) a[j] = sA[ty * 4 + j][kk];
#pragma unroll
            for (int i = 0; i < 8; ++i) b[i] = sB[kk][tx * 8 + i];
#pragma unroll
            for (int j = 0; j < 4; ++j)
#pragma unroll
                for (int i = 0; i < 8; ++i) c[j][i] = fmaf(a[j], b[i], c[j][i]);
        }
        __syncthreads();
    }

    // epilogue: bias (+ relu), coalesced float4 stores
#pragma unroll
    for (int j = 0; j < 4; ++j) {
        int n = row0 + ty * 4 + j;
#pragma unroll
        for (int i = 0; i < 8; ++i) {
            int o = tx * 8 + i;
            float v = c[j][i] + bias[o];
            if (RELU) v = fmaxf(v, 0.0f);
            out[(size_t)n * FDIM + o] = v;
        }
    }
}

extern "C" void kernel_launch(void* const* d_in, const int* in_sizes, int n_in,
                              void* d_out, int out_size, void* d_ws, size_t ws_size,
                              hipStream_t stream) {
    const float* x     = (const float*)d_in[0];
    const float* w1    = (const float*)d_in[1];
    const float* root1 = (const float*)d_in[2];
    const float* b1    = (const float*)d_in[3];
    const float* w2    = (const float*)d_in[4];
    const float* root2 = (const float*)d_in[5];
    const float* b2    = (const float*)d_in[6];
    const int*   ei    = (const int*)d_in[7];   // [2, E]
    const int*   et    = (const int*)d_in[8];   // [E]
    float* out = (float*)d_out;

    const int* srcv = ei;
    const int* dstv = ei + E_EDGES;

    // workspace layout
    float* acc = (float*)d_ws;                                    // N*R*F
    float* cnt = acc + (size_t)N_NODES * RREL * FDIM;             // N*R
    float* h   = cnt + (size_t)N_NODES * RREL;                    // N*F
    const size_t acc_cnt_bytes =
        ((size_t)N_NODES * RREL * FDIM + (size_t)N_NODES * RREL) * sizeof(float);

    const int scatter_blocks = E_EDGES / 8;   // 80000
    const int gemm_blocks    = N_NODES / BM;  // 625

    // ---- layer 1 ----
    hipMemsetAsync(acc, 0, acc_cnt_bytes, stream);
    scatter_kernel<<<scatter_blocks, 256, 0, stream>>>(x, srcv, dstv, et, acc, cnt);
    rgcn_gemm<1><<<gemm_blocks, 256, 0, stream>>>(acc, cnt, x, w1, root1, b1, h);

    // ---- layer 2 ----
    hipMemsetAsync(acc, 0, acc_cnt_bytes, stream);
    scatter_kernel<<<scatter_blocks, 256, 0, stream>>>(h, srcv, dstv, et, acc, cnt);
    rgcn_gemm<0><<<gemm_blocks, 256, 0, stream>>>(acc, cnt, h, w2, root2, b2, out);
}

// Round 2
// 869.677 us; speedup vs baseline: 3.5630x; 3.5630x over previous
//
#include <hip/hip_runtime.h>

#define N_NODES 40000
#define E_EDGES 640000
#define FDIM 128
#define RREL 4
#define NSEG (N_NODES * RREL)        // 160000
#define KBIG (RREL * FDIM)           // 512
#define KTOT (KBIG + FDIM)           // 640

// ---------------------------------------------------------------------------
// Step 1: histogram of segments (seg = dst*R + rel)
// ---------------------------------------------------------------------------
__global__ __launch_bounds__(256) void hist_kernel(const int* __restrict__ dst,
                                                   const int* __restrict__ et,
                                                   int* __restrict__ cnt) {
    int e = blockIdx.x * 256 + threadIdx.x;
    if (e >= E_EDGES) return;
    atomicAdd(&cnt[dst[e] * RREL + et[e]], 1);
}

// ---------------------------------------------------------------------------
// Step 2: exclusive scan of 160000 counts, single block of 1024 threads.
// Writes offs[0..NSEG] and cursor[i] = offs[i].
// ---------------------------------------------------------------------------
__global__ __launch_bounds__(1024) void scan_kernel(const int* __restrict__ cnt,
                                                    int* __restrict__ offs,
                                                    int* __restrict__ cursor) {
    __shared__ int part[1024];
    const int t = threadIdx.x;
    const int CH = (NSEG + 1023) / 1024;  // 157
    const int b = t * CH;
    const int e = min(b + CH, NSEG);
    int s = 0;
    for (int i = b; i < e; ++i) s += cnt[i];
    part[t] = s;
    __syncthreads();
    // Hillis-Steele inclusive scan
    for (int off = 1; off < 1024; off <<= 1) {
        int v = (t >= off) ? part[t - off] : 0;
        __syncthreads();
        part[t] += v;
        __syncthreads();
    }
    int run = (t == 0) ? 0 : part[t - 1];
    for (int i = b; i < e; ++i) {
        offs[i] = run;
        cursor[i] = run;
        run += cnt[i];
    }
    if (t == 1023) offs[NSEG] = run;
}

// ---------------------------------------------------------------------------
// Step 3: scatter edge source-ids into CSR slots
// ---------------------------------------------------------------------------
__global__ __launch_bounds__(256) void build_kernel(const int* __restrict__ src,
                                                    const int* __restrict__ dst,
                                                    const int* __restrict__ et,
                                                    int* __restrict__ cursor,
                                                    int* __restrict__ csr_src) {
    int e = blockIdx.x * 256 + threadIdx.x;
    if (e >= E_EDGES) return;
    int seg = dst[e] * RREL + et[e];
    int pos = atomicAdd(&cursor[seg], 1);
    csr_src[pos] = src[e];
}

// ---------------------------------------------------------------------------
// Step 4: atomic-free mean-aggregation. One wave (64 lanes) per segment;
// lane holds 2 floats of the 128-wide row. acc row written exactly once.
// ---------------------------------------------------------------------------
__global__ __launch_bounds__(256) void agg_kernel(const float* __restrict__ x,
                                                  const int* __restrict__ offs,
                                                  const int* __restrict__ csr_src,
                                                  float* __restrict__ acc) {
    int sid = blockIdx.x * 4 + (threadIdx.x >> 6);
    int lane = threadIdx.x & 63;
    int beg = offs[sid];
    int end = offs[sid + 1];
    float ax = 0.0f, ay = 0.0f;
    int p = beg;
    for (; p + 1 < end; p += 2) {
        int s0 = csr_src[p];
        int s1 = csr_src[p + 1];
        float2 v0 = *(const float2*)(x + (size_t)s0 * FDIM + lane * 2);
        float2 v1 = *(const float2*)(x + (size_t)s1 * FDIM + lane * 2);
        ax += v0.x; ay += v0.y;
        ax += v1.x; ay += v1.y;
    }
    if (p < end) {
        int s0 = csr_src[p];
        float2 v0 = *(const float2*)(x + (size_t)s0 * FDIM + lane * 2);
        ax += v0.x; ay += v0.y;
    }
    float rcp = 1.0f / (float)max(end - beg, 1);
    *(float2*)(acc + (size_t)sid * FDIM + lane * 2) = make_float2(ax * rcp, ay * rcp);
}

// ---------------------------------------------------------------------------
// Step 5: fused GEMM  out[n,:] = [acc(n,:) | x(n,:)] @ [w ; root] + bias
// BM=64 (40000 = 625*64, no guards), BN=128, BK=16, 128 threads (2 waves),
// per-thread 8x8 split as rows {ty*4, 32+ty*4} x cols {tx*4, 64+tx*4}.
// ---------------------------------------------------------------------------
#define BM 64
#define BK 16

template <int RELU>
__global__ __launch_bounds__(128) void rgcn_gemm(
    const float* __restrict__ acc, const float* __restrict__ xin,
    const float* __restrict__ w, const float* __restrict__ root,
    const float* __restrict__ bias, float* __restrict__ out) {
    __shared__ float sAT[BK][BM];    // transposed A tile [k][m]
    __shared__ float sB[BK][FDIM];   // [k][o]

    const int row0 = blockIdx.x * BM;
    const int tid = threadIdx.x;
    const int ty = (tid >> 4) & 7;   // 0..7
    const int tx = tid & 15;         // 0..15

    // A staging: thread -> row m = tid>>1 (0..63), k0 = (tid&1)*8
    const int am = tid >> 1;
    const int ak = (tid & 1) * 8;
    // B staging: thread -> k row bk = tid>>3 (0..15), col0 = (tid&7)*16
    const int bk = tid >> 3;
    const int bc = (tid & 7) * 16;

    float c[8][8];
#pragma unroll
    for (int i = 0; i < 8; ++i)
#pragma unroll
        for (int j = 0; j < 8; ++j) c[i][j] = 0.0f;

    for (int kb = 0; kb < KTOT; kb += BK) {
        // ---- load stage into registers (overlaps with previous compute) ----
        const float* Ap = (kb < KBIG)
            ? acc + (size_t)(row0 + am) * KBIG + (kb + ak)
            : xin + (size_t)(row0 + am) * FDIM + (kb - KBIG + ak);
        float4 a0 = ((const float4*)Ap)[0];
        float4 a1 = ((const float4*)Ap)[1];

        const float* Bp = (kb < KBIG)
            ? w + (size_t)(kb + bk) * FDIM + bc
            : root + (size_t)(kb - KBIG + bk) * FDIM + bc;
        float4 b0 = ((const float4*)Bp)[0];
        float4 b1 = ((const float4*)Bp)[1];
        float4 b2 = ((const float4*)Bp)[2];
        float4 b3 = ((const float4*)Bp)[3];

        __syncthreads();   // previous iteration's LDS reads complete

        sAT[ak + 0][am] = a0.x; sAT[ak + 1][am] = a0.y;
        sAT[ak + 2][am] = a0.z; sAT[ak + 3][am] = a0.w;
        sAT[ak + 4][am] = a1.x; sAT[ak + 5][am] = a1.y;
        sAT[ak + 6][am] = a1.z; sAT[ak + 7][am] = a1.w;
        *(float4*)&sB[bk][bc + 0]  = b0;
        *(float4*)&sB[bk][bc + 4]  = b1;
        *(float4*)&sB[bk][bc + 8]  = b2;
        *(float4*)&sB[bk][bc + 12] = b3;

        __syncthreads();

#pragma unroll
        for (int kk = 0; kk < BK; ++kk) {
            float4 ra0 = *(const float4*)&sAT[kk][ty * 4];
            float4 ra1 = *(const float4*)&sAT[kk][32 + ty * 4];
            float4 rb0 = *(const float4*)&sB[kk][tx * 4];
            float4 rb1 = *(const float4*)&sB[kk][64 + tx * 4];
            const float ar[8] = {ra0.x, ra0.y, ra0.z, ra0.w, ra1.x, ra1.y, ra1.z, ra1.w};
            const float br[8] = {rb0.x, rb0.y, rb0.z, rb0.w, rb1.x, rb1.y, rb1.z, rb1.w};
#pragma unroll
            for (int i = 0; i < 8; ++i)
#pragma unroll
                for (int j = 0; j < 8; ++j)
                    c[i][j] = fmaf(ar[i], br[j], c[i][j]);
        }
    }

    // ---- epilogue ----
    float4 bi0 = *(const float4*)&bias[tx * 4];
    float4 bi1 = *(const float4*)&bias[64 + tx * 4];
    const float bb[8] = {bi0.x, bi0.y, bi0.z, bi0.w, bi1.x, bi1.y, bi1.z, bi1.w};
#pragma unroll
    for (int ih = 0; ih < 2; ++ih)
#pragma unroll
        for (int i = 0; i < 4; ++i) {
            int r = row0 + ih * 32 + ty * 4 + i;
            int ci = ih * 4 + i;
            float4 v0, v1;
            v0.x = c[ci][0] + bb[0]; v0.y = c[ci][1] + bb[1];
            v0.z = c[ci][2] + bb[2]; v0.w = c[ci][3] + bb[3];
            v1.x = c[ci][4] + bb[4]; v1.y = c[ci][5] + bb[5];
            v1.z = c[ci][6] + bb[6]; v1.w = c[ci][7] + bb[7];
            if (RELU) {
                v0.x = fmaxf(v0.x, 0.f); v0.y = fmaxf(v0.y, 0.f);
                v0.z = fmaxf(v0.z, 0.f); v0.w = fmaxf(v0.w, 0.f);
                v1.x = fmaxf(v1.x, 0.f); v1.y = fmaxf(v1.y, 0.f);
                v1.z = fmaxf(v1.z, 0.f); v1.w = fmaxf(v1.w, 0.f);
            }
            *(float4*)&out[(size_t)r * FDIM + tx * 4] = v0;
            *(float4*)&out[(size_t)r * FDIM + 64 + tx * 4] = v1;
        }
}

extern "C" void kernel_launch(void* const* d_in, const int* in_sizes, int n_in,
                              void* d_out, int out_size, void* d_ws, size_t ws_size,
                              hipStream_t stream) {
    const float* x     = (const float*)d_in[0];
    const float* w1    = (const float*)d_in[1];
    const float* root1 = (const float*)d_in[2];
    const float* b1    = (const float*)d_in[3];
    const float* w2    = (const float*)d_in[4];
    const float* root2 = (const float*)d_in[5];
    const float* b2    = (const float*)d_in[6];
    const int*   ei    = (const int*)d_in[7];   // [2, E]
    const int*   et    = (const int*)d_in[8];   // [E]
    float* out = (float*)d_out;

    const int* srcv = ei;
    const int* dstv = ei + E_EDGES;

    // ---- workspace layout (element offsets; pad before float region) ----
    size_t io = 0;
    int* cnt_i  = (int*)d_ws + io;  io += NSEG;
    int* offs   = (int*)d_ws + io;  io += NSEG + 1;
    int* cursor = (int*)d_ws + io;  io += NSEG;
    int* csr    = (int*)d_ws + io;  io += E_EDGES;
    io = (io + 63) & ~(size_t)63;   // 256B-align float region
    float* acc = (float*)d_ws + io;                       // NSEG * FDIM
    float* h   = acc + (size_t)NSEG * FDIM;               // N * FDIM

    const int eb = (E_EDGES + 255) / 256;      // 2500
    const int ab = NSEG / 4;                   // 40000
    const int gb = N_NODES / BM;               // 625

    // ---- build CSR once (reused by both layers) ----
    hipMemsetAsync(cnt_i, 0, NSEG * sizeof(int), stream);
    hist_kernel<<<eb, 256, 0, stream>>>(dstv, et, cnt_i);
    scan_kernel<<<1, 1024, 0, stream>>>(cnt_i, offs, cursor);
    build_kernel<<<eb, 256, 0, stream>>>(srcv, dstv, et, cursor, csr);

    // ---- layer 1 ----
    agg_kernel<<<ab, 256, 0, stream>>>(x, offs, csr, acc);
    rgcn_gemm<1><<<gb, 128, 0, stream>>>(acc, x, w1, root1, b1, h);

    // ---- layer 2 ----
    agg_kernel<<<ab, 256, 0, stream>>>(h, offs, csr, acc);
    rgcn_gemm<0><<<gb, 128, 0, stream>>>(acc, h, w2, root2, b2, out);
}

// Round 3
// 536.144 us; speedup vs baseline: 5.7795x; 1.6221x over previous
//
#include <hip/hip_runtime.h>

#define N_NODES 40000
#define E_EDGES 640000
#define FDIM 128
#define RREL 4
#define NSEG (N_NODES * RREL)        // 160000
#define KBIG (RREL * FDIM)           // 512
#define KTOT (KBIG + FDIM)           // 640
#define SCAN_BLOCKS 625              // NSEG / 256

// ---------------------------------------------------------------------------
// Step 1: histogram of segments (seg = dst*R + rel)
// ---------------------------------------------------------------------------
__global__ __launch_bounds__(256) void hist_kernel(const int* __restrict__ dst,
                                                   const int* __restrict__ et,
                                                   int* __restrict__ cnt) {
    int e = blockIdx.x * 256 + threadIdx.x;
    if (e >= E_EDGES) return;
    atomicAdd(&cnt[dst[e] * RREL + et[e]], 1);
}

// ---------------------------------------------------------------------------
// Step 2a: per-block (256-elem) sums of cnt
// ---------------------------------------------------------------------------
__global__ __launch_bounds__(256) void scan_part(const int* __restrict__ cnt,
                                                 int* __restrict__ bsum) {
    __shared__ int s[256];
    int t = threadIdx.x;
    s[t] = cnt[blockIdx.x * 256 + t];
    __syncthreads();
#pragma unroll
    for (int off = 128; off > 0; off >>= 1) {
        if (t < off) s[t] += s[t + off];
        __syncthreads();
    }
    if (t == 0) bsum[blockIdx.x] = s[0];
}

// ---------------------------------------------------------------------------
// Step 2b: exclusive scan of the 625 block sums (single small block)
// ---------------------------------------------------------------------------
__global__ __launch_bounds__(1024) void scan_mid(const int* __restrict__ bsum,
                                                 int* __restrict__ bpre) {
    __shared__ int s[1024];
    int t = threadIdx.x;
    int v = (t < SCAN_BLOCKS) ? bsum[t] : 0;
    s[t] = v;
    __syncthreads();
    for (int off = 1; off < 1024; off <<= 1) {
        int u = (t >= off) ? s[t - off] : 0;
        __syncthreads();
        s[t] += u;
        __syncthreads();
    }
    if (t < SCAN_BLOCKS) bpre[t] = s[t] - v;  // exclusive prefix
}

// ---------------------------------------------------------------------------
// Step 2c: block-local exclusive scan + block prefix -> offs, cursor
// ---------------------------------------------------------------------------
__global__ __launch_bounds__(256) void scan_final(const int* __restrict__ cnt,
                                                  const int* __restrict__ bpre,
                                                  int* __restrict__ offs,
                                                  int* __restrict__ cursor) {
    __shared__ int s[256];
    int t = threadIdx.x;
    int g = blockIdx.x * 256 + t;
    int v = cnt[g];
    s[t] = v;
    __syncthreads();
    for (int off = 1; off < 256; off <<= 1) {
        int u = (t >= off) ? s[t - off] : 0;
        __syncthreads();
        s[t] += u;
        __syncthreads();
    }
    int ex = bpre[blockIdx.x] + s[t] - v;
    offs[g] = ex;
    cursor[g] = ex;
    if (blockIdx.x == 0 && t == 0) offs[NSEG] = E_EDGES;
}

// ---------------------------------------------------------------------------
// Step 3: scatter edge source-ids into CSR slots
// ---------------------------------------------------------------------------
__global__ __launch_bounds__(256) void build_kernel(const int* __restrict__ src,
                                                    const int* __restrict__ dst,
                                                    const int* __restrict__ et,
                                                    int* __restrict__ cursor,
                                                    int* __restrict__ csr_src) {
    int e = blockIdx.x * 256 + threadIdx.x;
    if (e >= E_EDGES) return;
    int seg = dst[e] * RREL + et[e];
    int pos = atomicAdd(&cursor[seg], 1);
    csr_src[pos] = src[e];
}

// ---------------------------------------------------------------------------
// Step 4: atomic-free mean-aggregation. One wave (64 lanes) per segment;
// lane holds 2 floats of the 128-wide row. acc row written exactly once.
// ---------------------------------------------------------------------------
__global__ __launch_bounds__(256) void agg_kernel(const float* __restrict__ x,
                                                  const int* __restrict__ offs,
                                                  const int* __restrict__ csr_src,
                                                  float* __restrict__ acc) {
    int sid = blockIdx.x * 4 + (threadIdx.x >> 6);
    int lane = threadIdx.x & 63;
    int beg = offs[sid];
    int end = offs[sid + 1];
    float ax = 0.0f, ay = 0.0f;
    int p = beg;
    for (; p + 1 < end; p += 2) {
        int s0 = csr_src[p];
        int s1 = csr_src[p + 1];
        float2 v0 = *(const float2*)(x + (size_t)s0 * FDIM + lane * 2);
        float2 v1 = *(const float2*)(x + (size_t)s1 * FDIM + lane * 2);
        ax += v0.x; ay += v0.y;
        ax += v1.x; ay += v1.y;
    }
    if (p < end) {
        int s0 = csr_src[p];
        float2 v0 = *(const float2*)(x + (size_t)s0 * FDIM + lane * 2);
        ax += v0.x; ay += v0.y;
    }
    float rcp = 1.0f / (float)max(end - beg, 1);
    *(float2*)(acc + (size_t)sid * FDIM + lane * 2) = make_float2(ax * rcp, ay * rcp);
}

// ---------------------------------------------------------------------------
// Step 5: fused GEMM  out[n,:] = [acc(n,:) | x(n,:)] @ [w ; root] + bias
// BM=64 (40000 = 625*64, no guards), BN=128, BK=16, 128 threads (2 waves),
// per-thread 8x8 split as rows {ty*4, 32+ty*4} x cols {tx*4, 64+tx*4}.
// B staging: flat-float4 order -> each wave writes one contiguous 1KB run
// (conflict-free ds_write_b128, perfectly coalesced global loads).
// ---------------------------------------------------------------------------
#define BM 64
#define BK 16

template <int RELU>
__global__ __launch_bounds__(128) void rgcn_gemm(
    const float* __restrict__ acc, const float* __restrict__ xin,
    const float* __restrict__ w, const float* __restrict__ root,
    const float* __restrict__ bias, float* __restrict__ out) {
    __shared__ float sAT[BK][BM];    // transposed A tile [k][m]
    __shared__ float sB[BK][FDIM];   // [k][o]

    const int row0 = blockIdx.x * BM;
    const int tid = threadIdx.x;
    const int ty = (tid >> 4) & 7;   // 0..7
    const int tx = tid & 15;         // 0..15

    // A staging: thread -> row m = tid>>1 (0..63), k0 = (tid&1)*8
    const int am = tid >> 1;
    const int ak = (tid & 1) * 8;

    float c[8][8];
#pragma unroll
    for (int i = 0; i < 8; ++i)
#pragma unroll
        for (int j = 0; j < 8; ++j) c[i][j] = 0.0f;

    for (int kb = 0; kb < KTOT; kb += BK) {
        // ---- load stage into registers (overlaps with previous compute) ----
        const float* Ap = (kb < KBIG)
            ? acc + (size_t)(row0 + am) * KBIG + (kb + ak)
            : xin + (size_t)(row0 + am) * FDIM + (kb - KBIG + ak);
        float4 a0 = ((const float4*)Ap)[0];
        float4 a1 = ((const float4*)Ap)[1];

        // B: 4 float4 per thread in flat sequential order
        float4 bv[4];
#pragma unroll
        for (int i = 0; i < 4; ++i) {
            int f = tid + i * 128;
            int brow = f >> 5;          // 0..15
            int bcol = (f & 31) * 4;    // 0..124
            const float* Bp = (kb < KBIG)
                ? w + (size_t)(kb + brow) * FDIM + bcol
                : root + (size_t)(kb - KBIG + brow) * FDIM + bcol;
            bv[i] = *(const float4*)Bp;
        }

        __syncthreads();   // previous iteration's LDS reads complete

        sAT[ak + 0][am] = a0.x; sAT[ak + 1][am] = a0.y;
        sAT[ak + 2][am] = a0.z; sAT[ak + 3][am] = a0.w;
        sAT[ak + 4][am] = a1.x; sAT[ak + 5][am] = a1.y;
        sAT[ak + 6][am] = a1.z; sAT[ak + 7][am] = a1.w;
#pragma unroll
        for (int i = 0; i < 4; ++i) {
            int f = tid + i * 128;
            int brow = f >> 5;
            int bcol = (f & 31) * 4;
            *(float4*)&sB[brow][bcol] = bv[i];
        }

        __syncthreads();

#pragma unroll
        for (int kk = 0; kk < BK; ++kk) {
            float4 ra0 = *(const float4*)&sAT[kk][ty * 4];
            float4 ra1 = *(const float4*)&sAT[kk][32 + ty * 4];
            float4 rb0 = *(const float4*)&sB[kk][tx * 4];
            float4 rb1 = *(const float4*)&sB[kk][64 + tx * 4];
            const float ar[8] = {ra0.x, ra0.y, ra0.z, ra0.w, ra1.x, ra1.y, ra1.z, ra1.w};
            const float br[8] = {rb0.x, rb0.y, rb0.z, rb0.w, rb1.x, rb1.y, rb1.z, rb1.w};
#pragma unroll
            for (int i = 0; i < 8; ++i)
#pragma unroll
                for (int j = 0; j < 8; ++j)
                    c[i][j] = fmaf(ar[i], br[j], c[i][j]);
        }
    }

    // ---- epilogue ----
    float4 bi0 = *(const float4*)&bias[tx * 4];
    float4 bi1 = *(const float4*)&bias[64 + tx * 4];
    const float bb[8] = {bi0.x, bi0.y, bi0.z, bi0.w, bi1.x, bi1.y, bi1.z, bi1.w};
#pragma unroll
    for (int ih = 0; ih < 2; ++ih)
#pragma unroll
        for (int i = 0; i < 4; ++i) {
            int r = row0 + ih * 32 + ty * 4 + i;
            int ci = ih * 4 + i;
            float4 v0, v1;
            v0.x = c[ci][0] + bb[0]; v0.y = c[ci][1] + bb[1];
            v0.z = c[ci][2] + bb[2]; v0.w = c[ci][3] + bb[3];
            v1.x = c[ci][4] + bb[4]; v1.y = c[ci][5] + bb[5];
            v1.z = c[ci][6] + bb[6]; v1.w = c[ci][7] + bb[7];
            if (RELU) {
                v0.x = fmaxf(v0.x, 0.f); v0.y = fmaxf(v0.y, 0.f);
                v0.z = fmaxf(v0.z, 0.f); v0.w = fmaxf(v0.w, 0.f);
                v1.x = fmaxf(v1.x, 0.f); v1.y = fmaxf(v1.y, 0.f);
                v1.z = fmaxf(v1.z, 0.f); v1.w = fmaxf(v1.w, 0.f);
            }
            *(float4*)&out[(size_t)r * FDIM + tx * 4] = v0;
            *(float4*)&out[(size_t)r * FDIM + 64 + tx * 4] = v1;
        }
}

extern "C" void kernel_launch(void* const* d_in, const int* in_sizes, int n_in,
                              void* d_out, int out_size, void* d_ws, size_t ws_size,
                              hipStream_t stream) {
    const float* x     = (const float*)d_in[0];
    const float* w1    = (const float*)d_in[1];
    const float* root1 = (const float*)d_in[2];
    const float* b1    = (const float*)d_in[3];
    const float* w2    = (const float*)d_in[4];
    const float* root2 = (const float*)d_in[5];
    const float* b2    = (const float*)d_in[6];
    const int*   ei    = (const int*)d_in[7];   // [2, E]
    const int*   et    = (const int*)d_in[8];   // [E]
    float* out = (float*)d_out;

    const int* srcv = ei;
    const int* dstv = ei + E_EDGES;

    // ---- workspace layout (element offsets; pad before float region) ----
    size_t io = 0;
    int* cnt_i  = (int*)d_ws + io;  io += NSEG;
    int* offs   = (int*)d_ws + io;  io += NSEG + 1;
    int* cursor = (int*)d_ws + io;  io += NSEG;
    int* csr    = (int*)d_ws + io;  io += E_EDGES;
    int* bsum   = (int*)d_ws + io;  io += SCAN_BLOCKS;
    int* bpre   = (int*)d_ws + io;  io += SCAN_BLOCKS;
    io = (io + 63) & ~(size_t)63;   // 256B-align float region
    float* acc = (float*)d_ws + io;                       // NSEG * FDIM
    float* h   = acc + (size_t)NSEG * FDIM;               // N * FDIM

    const int eb = (E_EDGES + 255) / 256;      // 2500
    const int ab = NSEG / 4;                   // 40000
    const int gb = N_NODES / BM;               // 625

    // ---- build CSR once (reused by both layers) ----
    hipMemsetAsync(cnt_i, 0, NSEG * sizeof(int), stream);
    hist_kernel<<<eb, 256, 0, stream>>>(dstv, et, cnt_i);
    scan_part<<<SCAN_BLOCKS, 256, 0, stream>>>(cnt_i, bsum);
    scan_mid<<<1, 1024, 0, stream>>>(bsum, bpre);
    scan_final<<<SCAN_BLOCKS, 256, 0, stream>>>(cnt_i, bpre, offs, cursor);
    build_kernel<<<eb, 256, 0, stream>>>(srcv, dstv, et, cursor, csr);

    // ---- layer 1 ----
    agg_kernel<<<ab, 256, 0, stream>>>(x, offs, csr, acc);
    rgcn_gemm<1><<<gb, 128, 0, stream>>>(acc, x, w1, root1, b1, h);

    // ---- layer 2 ----
    agg_kernel<<<ab, 256, 0, stream>>>(h, offs, csr, acc);
    rgcn_gemm<0><<<gb, 128, 0, stream>>>(acc, h, w2, root2, b2, out);
}

// Round 4
// 290.555 us; speedup vs baseline: 10.6645x; 1.8452x over previous
//
#include <hip/hip_runtime.h>

#define N_NODES 40000
#define E_EDGES 640000
#define FDIM 128
#define RREL 4
#define NSEG (N_NODES * RREL)        // 160000
#define OC 640                       // 4*128 relation cols + 128 root cols
#define SCAN_BLOCKS 625              // NSEG / 256

typedef __attribute__((ext_vector_type(8))) short s16x8;
typedef __attribute__((ext_vector_type(4))) float f32x4;

__device__ __forceinline__ unsigned short f2bf(float f) {
    unsigned int b = __float_as_uint(f);
    b = (b + 0x7FFFu + ((b >> 16) & 1u)) >> 16;   // round-to-nearest-even
    return (unsigned short)b;
}

// ---------------------------------------------------------------------------
// CSR build: histogram -> 3-pass scan -> slot scatter (seg = dst*R + rel)
// ---------------------------------------------------------------------------
__global__ __launch_bounds__(256) void hist_kernel(const int* __restrict__ dst,
                                                   const int* __restrict__ et,
                                                   int* __restrict__ cnt) {
    int e = blockIdx.x * 256 + threadIdx.x;
    if (e >= E_EDGES) return;
    atomicAdd(&cnt[dst[e] * RREL + et[e]], 1);
}

__global__ __launch_bounds__(256) void scan_part(const int* __restrict__ cnt,
                                                 int* __restrict__ bsum) {
    __shared__ int s[256];
    int t = threadIdx.x;
    s[t] = cnt[blockIdx.x * 256 + t];
    __syncthreads();
#pragma unroll
    for (int off = 128; off > 0; off >>= 1) {
        if (t < off) s[t] += s[t + off];
        __syncthreads();
    }
    if (t == 0) bsum[blockIdx.x] = s[0];
}

__global__ __launch_bounds__(1024) void scan_mid(const int* __restrict__ bsum,
                                                 int* __restrict__ bpre) {
    __shared__ int s[1024];
    int t = threadIdx.x;
    int v = (t < SCAN_BLOCKS) ? bsum[t] : 0;
    s[t] = v;
    __syncthreads();
    for (int off = 1; off < 1024; off <<= 1) {
        int u = (t >= off) ? s[t - off] : 0;
        __syncthreads();
        s[t] += u;
        __syncthreads();
    }
    if (t < SCAN_BLOCKS) bpre[t] = s[t] - v;  // exclusive prefix
}

__global__ __launch_bounds__(256) void scan_final(const int* __restrict__ cnt,
                                                  const int* __restrict__ bpre,
                                                  int* __restrict__ offs,
                                                  int* __restrict__ cursor) {
    __shared__ int s[256];
    int t = threadIdx.x;
    int g = blockIdx.x * 256 + t;
    int v = cnt[g];
    s[t] = v;
    __syncthreads();
    for (int off = 1; off < 256; off <<= 1) {
        int u = (t >= off) ? s[t - off] : 0;
        __syncthreads();
        s[t] += u;
        __syncthreads();
    }
    int ex = bpre[blockIdx.x] + s[t] - v;
    offs[g] = ex;
    cursor[g] = ex;
    if (blockIdx.x == 0 && t == 0) offs[NSEG] = E_EDGES;
}

__global__ __launch_bounds__(256) void build_kernel(const int* __restrict__ src,
                                                    const int* __restrict__ dst,
                                                    const int* __restrict__ et,
                                                    int* __restrict__ cursor,
                                                    int* __restrict__ csr_src) {
    int e = blockIdx.x * 256 + threadIdx.x;
    if (e >= E_EDGES) return;
    int seg = dst[e] * RREL + et[e];
    int pos = atomicAdd(&cursor[seg], 1);
    csr_src[pos] = src[e];
}

// ---------------------------------------------------------------------------
// fp32 -> bf16 converts
// ---------------------------------------------------------------------------
__global__ __launch_bounds__(256) void convert_x(const float* __restrict__ x,
                                                 unsigned short* __restrict__ xb) {
    int i = blockIdx.x * 256 + threadIdx.x;           // one float4 each
    float4 v = ((const float4*)x)[i];
    unsigned int p0 = (unsigned int)f2bf(v.x) | ((unsigned int)f2bf(v.y) << 16);
    unsigned int p1 = (unsigned int)f2bf(v.z) | ((unsigned int)f2bf(v.w) << 16);
    ((uint2*)xb)[i] = make_uint2(p0, p1);
}

// WT[oc][k] = B[k][oc], B = [w_0 | w_1 | w_2 | w_3 | root] (128 x 640), bf16
__global__ __launch_bounds__(256) void convert_w(const float* __restrict__ w1,
                                                 const float* __restrict__ r1,
                                                 const float* __restrict__ w2,
                                                 const float* __restrict__ r2,
                                                 unsigned short* __restrict__ wt1,
                                                 unsigned short* __restrict__ wt2) {
    int t = blockIdx.x * 256 + threadIdx.x;           // 0 .. 2*81920-1
    int layer = (t >= OC * FDIM);
    int tl = layer ? t - OC * FDIM : t;
    int oc = tl >> 7;
    int k  = tl & 127;
    const float* w = layer ? w2 : w1;
    const float* r = layer ? r2 : r1;
    float v;
    if (oc < RREL * FDIM)
        v = w[((size_t)(oc >> 7) * FDIM + k) * FDIM + (oc & 127)];
    else
        v = r[(size_t)k * FDIM + (oc - RREL * FDIM)];
    (layer ? wt2 : wt1)[tl] = f2bf(v);
}

// ---------------------------------------------------------------------------
// MFMA GEMM: Y[N][640] = A[N][128] @ B[128][640], all bf16, fp32 accum.
// Single K stage (BK = K = 128), one barrier. Fragment-linear LDS layout:
// every ds_read/ds_write is base + lane*16B -> conflict-free.
// Block: 64 rows x 128 cols, 4 waves (2x2), per wave 2x4 16x16 frags x 4 ksteps.
// ---------------------------------------------------------------------------
__global__ __launch_bounds__(256) void mfma_gemm(
    const unsigned short* __restrict__ A,    // [N][128] bf16
    const unsigned short* __restrict__ WT,   // [640][128] bf16 (B transposed)
    unsigned short* __restrict__ Y) {        // [N][640] bf16
    __shared__ unsigned short sA[16 * 512];  // 16 blocks of (64 lanes x 8 bf16)
    __shared__ unsigned short sB[32 * 512];  // 32 blocks

    const int tid = threadIdx.x;
    const int wid = tid >> 6, lane = tid & 63;
    const int lrow = lane & 15, lk8 = lane >> 4;
    const int row0 = blockIdx.x * 64;
    const int oc0  = blockIdx.y * 128;
    const int wr = wid >> 1, wc = wid & 1;

    // stage 48 KB: 48 frag-blocks, 12 per wave, 16 B per lane each
#pragma unroll
    for (int it = 0; it < 12; ++it) {
        int bid = wid * 12 + it;
        const unsigned short* gp;
        unsigned short* lp;
        if (bid < 16) {                       // A blocks: (mt, kt)
            int mt = bid >> 2, kt = bid & 3;
            gp = A + (size_t)(row0 + mt * 16 + lrow) * FDIM + kt * 32 + lk8 * 8;
            lp = &sA[bid * 512 + lane * 8];
        } else {                              // B blocks: (nt, kt)
            int b = bid - 16, nt = b >> 2, kt = b & 3;
            gp = WT + (size_t)(oc0 + nt * 16 + lrow) * FDIM + kt * 32 + lk8 * 8;
            lp = &sB[b * 512 + lane * 8];
        }
        *(uint4*)lp = *(const uint4*)gp;
    }
    __syncthreads();

    f32x4 acc[2][4];
#pragma unroll
    for (int i = 0; i < 2; ++i)
#pragma unroll
        for (int j = 0; j < 4; ++j) acc[i][j] = (f32x4){0.f, 0.f, 0.f, 0.f};

#pragma unroll
    for (int kt = 0; kt < 4; ++kt) {
        s16x8 a[2], b[4];
#pragma unroll
        for (int i = 0; i < 2; ++i)
            a[i] = *(const s16x8*)&sA[(((wr * 2 + i) * 4) + kt) * 512 + lane * 8];
#pragma unroll
        for (int j = 0; j < 4; ++j)
            b[j] = *(const s16x8*)&sB[(((wc * 4 + j) * 4) + kt) * 512 + lane * 8];
#pragma unroll
        for (int i = 0; i < 2; ++i)
#pragma unroll
            for (int j = 0; j < 4; ++j)
                acc[i][j] = __builtin_amdgcn_mfma_f32_16x16x32_bf16(a[i], b[j], acc[i][j], 0, 0, 0);
    }

    // epilogue: C/D layout col=lane&15, row=(lane>>4)*4+reg  [m89-verified]
#pragma unroll
    for (int i = 0; i < 2; ++i)
#pragma unroll
        for (int j = 0; j < 4; ++j)
#pragma unroll
            for (int q = 0; q < 4; ++q) {
                int row = row0 + wr * 32 + i * 16 + lk8 * 4 + q;
                int col = oc0 + wc * 64 + j * 16 + lrow;
                Y[(size_t)row * OC + col] = f2bf(acc[i][j][q]);
            }
}

// ---------------------------------------------------------------------------
// Fused aggregate: out[n] = act( sum_r mean_{e in (n,r)} y[src_e, r*128:+128]
//                                + y[n, 512:640] + bias )
// One wave per node; lane owns a bf16x2 column pair (4 B gather per edge).
// ---------------------------------------------------------------------------
template <int RELU, int OUT_BF16>
__global__ __launch_bounds__(256) void agg_kernel(
    const unsigned short* __restrict__ y,
    const int* __restrict__ offs, const int* __restrict__ csr,
    const float* __restrict__ bias,
    unsigned short* __restrict__ hout, float* __restrict__ fout) {
    int node = blockIdx.x * 4 + (threadIdx.x >> 6);
    int lane = threadIdx.x & 63;
    int base = node * RREL;
    float t0 = 0.f, t1 = 0.f;
#pragma unroll
    for (int r = 0; r < RREL; ++r) {
        int b = offs[base + r], e = offs[base + r + 1];
        float s0 = 0.f, s1 = 0.f;
        for (int p = b; p < e; ++p) {
            int s = csr[p];
            unsigned int v = *(const unsigned int*)(y + (size_t)s * OC + r * FDIM + lane * 2);
            s0 += __uint_as_float(v << 16);
            s1 += __uint_as_float(v & 0xFFFF0000u);
        }
        float rcp = 1.0f / (float)max(e - b, 1);
        t0 += s0 * rcp;
        t1 += s1 * rcp;
    }
    unsigned int v = *(const unsigned int*)(y + (size_t)node * OC + RREL * FDIM + lane * 2);
    float2 bb = *(const float2*)(bias + lane * 2);
    t0 += __uint_as_float(v << 16) + bb.x;
    t1 += __uint_as_float(v & 0xFFFF0000u) + bb.y;
    if (RELU) { t0 = fmaxf(t0, 0.f); t1 = fmaxf(t1, 0.f); }
    if (OUT_BF16) {
        unsigned int pk = (unsigned int)f2bf(t0) | ((unsigned int)f2bf(t1) << 16);
        *(unsigned int*)(hout + (size_t)node * FDIM + lane * 2) = pk;
    } else {
        *(float2*)(fout + (size_t)node * FDIM + lane * 2) = make_float2(t0, t1);
    }
}

extern "C" void kernel_launch(void* const* d_in, const int* in_sizes, int n_in,
                              void* d_out, int out_size, void* d_ws, size_t ws_size,
                              hipStream_t stream) {
    const float* x     = (const float*)d_in[0];
    const float* w1    = (const float*)d_in[1];
    const float* root1 = (const float*)d_in[2];
    const float* b1    = (const float*)d_in[3];
    const float* w2    = (const float*)d_in[4];
    const float* root2 = (const float*)d_in[5];
    const float* b2    = (const float*)d_in[6];
    const int*   ei    = (const int*)d_in[7];   // [2, E]
    const int*   et    = (const int*)d_in[8];   // [E]
    float* out = (float*)d_out;

    const int* srcv = ei;
    const int* dstv = ei + E_EDGES;

    // ---- workspace layout ----
    size_t io = 0;
    int* cnt_i  = (int*)d_ws + io;  io += NSEG;
    int* offs   = (int*)d_ws + io;  io += NSEG + 1;
    int* cursor = (int*)d_ws + io;  io += NSEG;
    int* csr    = (int*)d_ws + io;  io += E_EDGES;
    int* bsum   = (int*)d_ws + io;  io += SCAN_BLOCKS;
    int* bpre   = (int*)d_ws + io;  io += SCAN_BLOCKS;
    io = (io + 63) & ~(size_t)63;                       // 256B-align
    unsigned short* us  = (unsigned short*)((int*)d_ws + io);
    size_t uo = 0;
    unsigned short* xb  = us + uo;  uo += (size_t)N_NODES * FDIM;   // bf16 x
    unsigned short* wt1 = us + uo;  uo += (size_t)OC * FDIM;        // bf16 B1^T
    unsigned short* wt2 = us + uo;  uo += (size_t)OC * FDIM;        // bf16 B2^T
    unsigned short* h   = us + uo;  uo += (size_t)N_NODES * FDIM;   // bf16 hidden
    unsigned short* y   = us + uo;  uo += (size_t)N_NODES * OC;     // bf16 y (reused)

    const int eb = (E_EDGES + 255) / 256;      // 2500

    // ---- build CSR once (reused by both layers) ----
    hipMemsetAsync(cnt_i, 0, NSEG * sizeof(int), stream);
    hist_kernel<<<eb, 256, 0, stream>>>(dstv, et, cnt_i);
    scan_part<<<SCAN_BLOCKS, 256, 0, stream>>>(cnt_i, bsum);
    scan_mid<<<1, 1024, 0, stream>>>(bsum, bpre);
    scan_final<<<SCAN_BLOCKS, 256, 0, stream>>>(cnt_i, bpre, offs, cursor);
    build_kernel<<<eb, 256, 0, stream>>>(srcv, dstv, et, cursor, csr);

    // ---- converts ----
    convert_x<<<(N_NODES * FDIM / 4) / 256, 256, 0, stream>>>(x, xb);
    convert_w<<<(2 * OC * FDIM) / 256, 256, 0, stream>>>(w1, root1, w2, root2, wt1, wt2);

    // ---- layer 1 ----
    mfma_gemm<<<dim3(N_NODES / 64, OC / 128), 256, 0, stream>>>(xb, wt1, y);
    agg_kernel<1, 1><<<N_NODES / 4, 256, 0, stream>>>(y, offs, csr, b1, h, nullptr);

    // ---- layer 2 ----
    mfma_gemm<<<dim3(N_NODES / 64, OC / 128), 256, 0, stream>>>(h, wt2, y);
    agg_kernel<0, 0><<<N_NODES / 4, 256, 0, stream>>>(y, offs, csr, b2, nullptr, out);
}

// Round 5
// 228.438 us; speedup vs baseline: 13.5644x; 1.2719x over previous
//
#include <hip/hip_runtime.h>

#define N_NODES 40000
#define E_EDGES 640000
#define FDIM 128
#define RREL 4
#define NSEG (N_NODES * RREL)        // 160000
#define OC 640                       // 4*128 relation cols + 128 root cols
#define SCAN_BLOCKS 625              // NSEG / 256

typedef __attribute__((ext_vector_type(8))) short s16x8;
typedef __attribute__((ext_vector_type(4))) float f32x4;

__device__ __forceinline__ unsigned short f2bf(float f) {
    unsigned int b = __float_as_uint(f);
    b = (b + 0x7FFFu + ((b >> 16) & 1u)) >> 16;   // round-to-nearest-even
    return (unsigned short)b;
}
__device__ __forceinline__ float bflo(unsigned int v) { return __uint_as_float(v << 16); }
__device__ __forceinline__ float bfhi(unsigned int v) { return __uint_as_float(v & 0xFFFF0000u); }

// ---------------------------------------------------------------------------
// CSR build: histogram -> 3-pass scan -> slot scatter (seg = dst*R + rel)
// ---------------------------------------------------------------------------
__global__ __launch_bounds__(256) void hist_kernel(const int* __restrict__ dst,
                                                   const int* __restrict__ et,
                                                   int* __restrict__ cnt) {
    int e = blockIdx.x * 256 + threadIdx.x;
    if (e >= E_EDGES) return;
    atomicAdd(&cnt[dst[e] * RREL + et[e]], 1);
}

__global__ __launch_bounds__(256) void scan_part(const int* __restrict__ cnt,
                                                 int* __restrict__ bsum) {
    __shared__ int s[256];
    int t = threadIdx.x;
    s[t] = cnt[blockIdx.x * 256 + t];
    __syncthreads();
#pragma unroll
    for (int off = 128; off > 0; off >>= 1) {
        if (t < off) s[t] += s[t + off];
        __syncthreads();
    }
    if (t == 0) bsum[blockIdx.x] = s[0];
}

__global__ __launch_bounds__(1024) void scan_mid(const int* __restrict__ bsum,
                                                 int* __restrict__ bpre) {
    __shared__ int s[1024];
    int t = threadIdx.x;
    int v = (t < SCAN_BLOCKS) ? bsum[t] : 0;
    s[t] = v;
    __syncthreads();
    for (int off = 1; off < 1024; off <<= 1) {
        int u = (t >= off) ? s[t - off] : 0;
        __syncthreads();
        s[t] += u;
        __syncthreads();
    }
    if (t < SCAN_BLOCKS) bpre[t] = s[t] - v;  // exclusive prefix
}

__global__ __launch_bounds__(256) void scan_final(const int* __restrict__ cnt,
                                                  const int* __restrict__ bpre,
                                                  int* __restrict__ offs,
                                                  int* __restrict__ cursor) {
    __shared__ int s[256];
    int t = threadIdx.x;
    int g = blockIdx.x * 256 + t;
    int v = cnt[g];
    s[t] = v;
    __syncthreads();
    for (int off = 1; off < 256; off <<= 1) {
        int u = (t >= off) ? s[t - off] : 0;
        __syncthreads();
        s[t] += u;
        __syncthreads();
    }
    int ex = bpre[blockIdx.x] + s[t] - v;
    offs[g] = ex;
    cursor[g] = ex;
    if (blockIdx.x == 0 && t == 0) offs[NSEG] = E_EDGES;
}

__global__ __launch_bounds__(256) void build_kernel(const int* __restrict__ src,
                                                    const int* __restrict__ dst,
                                                    const int* __restrict__ et,
                                                    int* __restrict__ cursor,
                                                    int* __restrict__ csr_src) {
    int e = blockIdx.x * 256 + threadIdx.x;
    if (e >= E_EDGES) return;
    int seg = dst[e] * RREL + et[e];
    int pos = atomicAdd(&cursor[seg], 1);
    csr_src[pos] = src[e];
}

// ---------------------------------------------------------------------------
// fp32 -> bf16 converts
// ---------------------------------------------------------------------------
__global__ __launch_bounds__(256) void convert_x(const float* __restrict__ x,
                                                 unsigned short* __restrict__ xb) {
    int i = blockIdx.x * 256 + threadIdx.x;           // one float4 each
    float4 v = ((const float4*)x)[i];
    unsigned int p0 = (unsigned int)f2bf(v.x) | ((unsigned int)f2bf(v.y) << 16);
    unsigned int p1 = (unsigned int)f2bf(v.z) | ((unsigned int)f2bf(v.w) << 16);
    ((uint2*)xb)[i] = make_uint2(p0, p1);
}

// WT[oc][k] = B[k][oc], B = [w_0 | w_1 | w_2 | w_3 | root] (128 x 640), bf16
__global__ __launch_bounds__(256) void convert_w(const float* __restrict__ w1,
                                                 const float* __restrict__ r1,
                                                 const float* __restrict__ w2,
                                                 const float* __restrict__ r2,
                                                 unsigned short* __restrict__ wt1,
                                                 unsigned short* __restrict__ wt2) {
    int t = blockIdx.x * 256 + threadIdx.x;           // 0 .. 2*81920-1
    int layer = (t >= OC * FDIM);
    int tl = layer ? t - OC * FDIM : t;
    int oc = tl >> 7;
    int k  = tl & 127;
    const float* w = layer ? w2 : w1;
    const float* r = layer ? r2 : r1;
    float v;
    if (oc < RREL * FDIM)
        v = w[((size_t)(oc >> 7) * FDIM + k) * FDIM + (oc & 127)];
    else
        v = r[(size_t)k * FDIM + (oc - RREL * FDIM)];
    (layer ? wt2 : wt1)[tl] = f2bf(v);
}

// ---------------------------------------------------------------------------
// MFMA GEMM: Y[N][640] = A[N][128] @ B[128][640], all bf16, fp32 accum.
// Single K stage (BK = K = 128), one barrier. Fragment-linear LDS layout:
// every ds_read/ds_write is base + lane*16B -> conflict-free.
// Block: 64 rows x 128 cols, 4 waves (2x2), per wave 2x4 16x16 frags x 4 ksteps.
// ---------------------------------------------------------------------------
__global__ __launch_bounds__(256) void mfma_gemm(
    const unsigned short* __restrict__ A,    // [N][128] bf16
    const unsigned short* __restrict__ WT,   // [640][128] bf16 (B transposed)
    unsigned short* __restrict__ Y) {        // [N][640] bf16
    __shared__ unsigned short sA[16 * 512];  // 16 blocks of (64 lanes x 8 bf16)
    __shared__ unsigned short sB[32 * 512];  // 32 blocks

    const int tid = threadIdx.x;
    const int wid = tid >> 6, lane = tid & 63;
    const int lrow = lane & 15, lk8 = lane >> 4;
    const int row0 = blockIdx.x * 64;
    const int oc0  = blockIdx.y * 128;
    const int wr = wid >> 1, wc = wid & 1;

    // stage 48 KB: 48 frag-blocks, 12 per wave, 16 B per lane each
#pragma unroll
    for (int it = 0; it < 12; ++it) {
        int bid = wid * 12 + it;
        const unsigned short* gp;
        unsigned short* lp;
        if (bid < 16) {                       // A blocks: (mt, kt)
            int mt = bid >> 2, kt = bid & 3;
            gp = A + (size_t)(row0 + mt * 16 + lrow) * FDIM + kt * 32 + lk8 * 8;
            lp = &sA[bid * 512 + lane * 8];
        } else {                              // B blocks: (nt, kt)
            int b = bid - 16, nt = b >> 2, kt = b & 3;
            gp = WT + (size_t)(oc0 + nt * 16 + lrow) * FDIM + kt * 32 + lk8 * 8;
            lp = &sB[b * 512 + lane * 8];
        }
        *(uint4*)lp = *(const uint4*)gp;
    }
    __syncthreads();

    f32x4 acc[2][4];
#pragma unroll
    for (int i = 0; i < 2; ++i)
#pragma unroll
        for (int j = 0; j < 4; ++j) acc[i][j] = (f32x4){0.f, 0.f, 0.f, 0.f};

#pragma unroll
    for (int kt = 0; kt < 4; ++kt) {
        s16x8 a[2], b[4];
#pragma unroll
        for (int i = 0; i < 2; ++i)
            a[i] = *(const s16x8*)&sA[(((wr * 2 + i) * 4) + kt) * 512 + lane * 8];
#pragma unroll
        for (int j = 0; j < 4; ++j)
            b[j] = *(const s16x8*)&sB[(((wc * 4 + j) * 4) + kt) * 512 + lane * 8];
#pragma unroll
        for (int i = 0; i < 2; ++i)
#pragma unroll
            for (int j = 0; j < 4; ++j)
                acc[i][j] = __builtin_amdgcn_mfma_f32_16x16x32_bf16(a[i], b[j], acc[i][j], 0, 0, 0);
    }

    // epilogue: C/D layout col=lane&15, row=(lane>>4)*4+reg  [m89-verified]
#pragma unroll
    for (int i = 0; i < 2; ++i)
#pragma unroll
        for (int j = 0; j < 4; ++j)
#pragma unroll
            for (int q = 0; q < 4; ++q) {
                int row = row0 + wr * 32 + i * 16 + lk8 * 4 + q;
                int col = oc0 + wc * 64 + j * 16 + lrow;
                Y[(size_t)row * OC + col] = f2bf(acc[i][j][q]);
            }
}

// ---------------------------------------------------------------------------
// Fused aggregate v2: one wave per node, split into 4 x 16-lane edge-groups.
// Group g handles edges p = b+g, b+g+4, ... with dwordx4 (16B/lane) gathers,
// unrolled x2 -> up to 8 independent 1KB wave-gathers in flight.
// Mean rescale is group-local; one shfl_xor(16,32) butterfly merges groups.
// ---------------------------------------------------------------------------
template <int RELU, int OUT_BF16>
__global__ __launch_bounds__(256) void agg_kernel(
    const unsigned short* __restrict__ y,
    const int* __restrict__ offs, const int* __restrict__ csr,
    const float* __restrict__ bias,
    unsigned short* __restrict__ hout, float* __restrict__ fout) {
    const int node = blockIdx.x * 4 + (threadIdx.x >> 6);
    const int lane = threadIdx.x & 63;
    const int g  = lane >> 4;    // edge-group 0..3
    const int fl = lane & 15;    // features fl*8 .. fl*8+7
    const int base = node * RREL;

    float t[8];
#pragma unroll
    for (int j = 0; j < 8; ++j) t[j] = 0.f;

#pragma unroll
    for (int r = 0; r < RREL; ++r) {
        const int b = offs[base + r], e = offs[base + r + 1];
        const unsigned short* yr = y + (size_t)r * FDIM + fl * 8;
        float s[8];
#pragma unroll
        for (int j = 0; j < 8; ++j) s[j] = 0.f;
        int p = b + g;
        for (; p + 4 < e; p += 8) {
            int i0 = csr[p];
            int i1 = csr[p + 4];
            uint4 v0 = *(const uint4*)(yr + (size_t)i0 * OC);
            uint4 v1 = *(const uint4*)(yr + (size_t)i1 * OC);
            s[0] += bflo(v0.x); s[1] += bfhi(v0.x);
            s[2] += bflo(v0.y); s[3] += bfhi(v0.y);
            s[4] += bflo(v0.z); s[5] += bfhi(v0.z);
            s[6] += bflo(v0.w); s[7] += bfhi(v0.w);
            s[0] += bflo(v1.x); s[1] += bfhi(v1.x);
            s[2] += bflo(v1.y); s[3] += bfhi(v1.y);
            s[4] += bflo(v1.z); s[5] += bfhi(v1.z);
            s[6] += bflo(v1.w); s[7] += bfhi(v1.w);
        }
        if (p < e) {
            int i0 = csr[p];
            uint4 v0 = *(const uint4*)(yr + (size_t)i0 * OC);
            s[0] += bflo(v0.x); s[1] += bfhi(v0.x);
            s[2] += bflo(v0.y); s[3] += bfhi(v0.y);
            s[4] += bflo(v0.z); s[5] += bfhi(v0.z);
            s[6] += bflo(v0.w); s[7] += bfhi(v0.w);
        }
        float rcp = 1.0f / (float)max(e - b, 1);
#pragma unroll
        for (int j = 0; j < 8; ++j) t[j] += s[j] * rcp;
    }

    // merge the 4 edge-groups (2-step butterfly across lane bits 4,5)
#pragma unroll
    for (int j = 0; j < 8; ++j) {
        t[j] += __shfl_xor(t[j], 16);
        t[j] += __shfl_xor(t[j], 32);
    }

    // root + bias (+relu); all lanes compute, group 0 writes
    uint4 rv = *(const uint4*)(y + (size_t)node * OC + RREL * FDIM + fl * 8);
    float4 bb0 = *(const float4*)(bias + fl * 8);
    float4 bb1 = *(const float4*)(bias + fl * 8 + 4);
    t[0] += bflo(rv.x) + bb0.x; t[1] += bfhi(rv.x) + bb0.y;
    t[2] += bflo(rv.y) + bb0.z; t[3] += bfhi(rv.y) + bb0.w;
    t[4] += bflo(rv.z) + bb1.x; t[5] += bfhi(rv.z) + bb1.y;
    t[6] += bflo(rv.w) + bb1.z; t[7] += bfhi(rv.w) + bb1.w;
    if (RELU) {
#pragma unroll
        for (int j = 0; j < 8; ++j) t[j] = fmaxf(t[j], 0.f);
    }
    if (g == 0) {
        if (OUT_BF16) {
            uint4 pk;
            pk.x = (unsigned int)f2bf(t[0]) | ((unsigned int)f2bf(t[1]) << 16);
            pk.y = (unsigned int)f2bf(t[2]) | ((unsigned int)f2bf(t[3]) << 16);
            pk.z = (unsigned int)f2bf(t[4]) | ((unsigned int)f2bf(t[5]) << 16);
            pk.w = (unsigned int)f2bf(t[6]) | ((unsigned int)f2bf(t[7]) << 16);
            *(uint4*)(hout + (size_t)node * FDIM + fl * 8) = pk;
        } else {
            float* op = fout + (size_t)node * FDIM + fl * 8;
            *(float4*)op       = make_float4(t[0], t[1], t[2], t[3]);
            *(float4*)(op + 4) = make_float4(t[4], t[5], t[6], t[7]);
        }
    }
}

extern "C" void kernel_launch(void* const* d_in, const int* in_sizes, int n_in,
                              void* d_out, int out_size, void* d_ws, size_t ws_size,
                              hipStream_t stream) {
    const float* x     = (const float*)d_in[0];
    const float* w1    = (const float*)d_in[1];
    const float* root1 = (const float*)d_in[2];
    const float* b1    = (const float*)d_in[3];
    const float* w2    = (const float*)d_in[4];
    const float* root2 = (const float*)d_in[5];
    const float* b2    = (const float*)d_in[6];
    const int*   ei    = (const int*)d_in[7];   // [2, E]
    const int*   et    = (const int*)d_in[8];   // [E]
    float* out = (float*)d_out;

    const int* srcv = ei;
    const int* dstv = ei + E_EDGES;

    // ---- workspace layout ----
    size_t io = 0;
    int* cnt_i  = (int*)d_ws + io;  io += NSEG;
    int* offs   = (int*)d_ws + io;  io += NSEG + 1;
    int* cursor = (int*)d_ws + io;  io += NSEG;
    int* csr    = (int*)d_ws + io;  io += E_EDGES;
    int* bsum   = (int*)d_ws + io;  io += SCAN_BLOCKS;
    int* bpre   = (int*)d_ws + io;  io += SCAN_BLOCKS;
    io = (io + 63) & ~(size_t)63;                       // 256B-align
    unsigned short* us  = (unsigned short*)((int*)d_ws + io);
    size_t uo = 0;
    unsigned short* xb  = us + uo;  uo += (size_t)N_NODES * FDIM;   // bf16 x
    unsigned short* wt1 = us + uo;  uo += (size_t)OC * FDIM;        // bf16 B1^T
    unsigned short* wt2 = us + uo;  uo += (size_t)OC * FDIM;        // bf16 B2^T
    unsigned short* h   = us + uo;  uo += (size_t)N_NODES * FDIM;   // bf16 hidden
    unsigned short* y   = us + uo;  uo += (size_t)N_NODES * OC;     // bf16 y (reused)

    const int eb = (E_EDGES + 255) / 256;      // 2500

    // ---- build CSR once (reused by both layers) ----
    hipMemsetAsync(cnt_i, 0, NSEG * sizeof(int), stream);
    hist_kernel<<<eb, 256, 0, stream>>>(dstv, et, cnt_i);
    scan_part<<<SCAN_BLOCKS, 256, 0, stream>>>(cnt_i, bsum);
    scan_mid<<<1, 1024, 0, stream>>>(bsum, bpre);
    scan_final<<<SCAN_BLOCKS, 256, 0, stream>>>(cnt_i, bpre, offs, cursor);
    build_kernel<<<eb, 256, 0, stream>>>(srcv, dstv, et, cursor, csr);

    // ---- converts ----
    convert_x<<<(N_NODES * FDIM / 4) / 256, 256, 0, stream>>>(x, xb);
    convert_w<<<(2 * OC * FDIM) / 256, 256, 0, stream>>>(w1, root1, w2, root2, wt1, wt2);

    // ---- layer 1 ----
    mfma_gemm<<<dim3(N_NODES / 64, OC / 128), 256, 0, stream>>>(xb, wt1, y);
    agg_kernel<1, 1><<<N_NODES / 4, 256, 0, stream>>>(y, offs, csr, b1, h, nullptr);

    // ---- layer 2 ----
    mfma_gemm<<<dim3(N_NODES / 64, OC / 128), 256, 0, stream>>>(h, wt2, y);
    agg_kernel<0, 0><<<N_NODES / 4, 256, 0, stream>>>(y, offs, csr, b2, nullptr, out);
}

// Round 6
// 205.511 us; speedup vs baseline: 15.0777x; 1.1116x over previous
//
#include <hip/hip_runtime.h>

#define N_NODES 40000
#define E_EDGES 640000
#define FDIM 128
#define RREL 4
#define NSEG (N_NODES * RREL)        // 160000
#define KBIG (RREL * FDIM)           // 512
#define KTOT (KBIG + FDIM)           // 640
#define SCAN_BLOCKS 625              // NSEG / 256

typedef __attribute__((ext_vector_type(8))) short s16x8;
typedef __attribute__((ext_vector_type(4))) float f32x4;

__device__ __forceinline__ unsigned short f2bf(float f) {
    unsigned int b = __float_as_uint(f);
    b = (b + 0x7FFFu + ((b >> 16) & 1u)) >> 16;   // round-to-nearest-even
    return (unsigned short)b;
}
__device__ __forceinline__ float bflo(unsigned int v) { return __uint_as_float(v << 16); }
__device__ __forceinline__ float bfhi(unsigned int v) { return __uint_as_float(v & 0xFFFF0000u); }

// ---------------------------------------------------------------------------
// Zero-fill (replaces hipMemsetAsync's 42us fillBufferAligned)
// ---------------------------------------------------------------------------
__global__ __launch_bounds__(256) void fill_zero(int* __restrict__ p) {
    p[blockIdx.x * 256 + threadIdx.x] = 0;
}

// ---------------------------------------------------------------------------
// CSR build: histogram -> 3-pass scan -> slot scatter (seg = dst*R + rel)
// ---------------------------------------------------------------------------
__global__ __launch_bounds__(256) void hist_kernel(const int* __restrict__ dst,
                                                   const int* __restrict__ et,
                                                   int* __restrict__ cnt) {
    int e = blockIdx.x * 256 + threadIdx.x;
    if (e >= E_EDGES) return;
    atomicAdd(&cnt[dst[e] * RREL + et[e]], 1);
}

__global__ __launch_bounds__(256) void scan_part(const int* __restrict__ cnt,
                                                 int* __restrict__ bsum) {
    __shared__ int s[256];
    int t = threadIdx.x;
    s[t] = cnt[blockIdx.x * 256 + t];
    __syncthreads();
#pragma unroll
    for (int off = 128; off > 0; off >>= 1) {
        if (t < off) s[t] += s[t + off];
        __syncthreads();
    }
    if (t == 0) bsum[blockIdx.x] = s[0];
}

__global__ __launch_bounds__(1024) void scan_mid(const int* __restrict__ bsum,
                                                 int* __restrict__ bpre) {
    __shared__ int s[1024];
    int t = threadIdx.x;
    int v = (t < SCAN_BLOCKS) ? bsum[t] : 0;
    s[t] = v;
    __syncthreads();
    for (int off = 1; off < 1024; off <<= 1) {
        int u = (t >= off) ? s[t - off] : 0;
        __syncthreads();
        s[t] += u;
        __syncthreads();
    }
    if (t < SCAN_BLOCKS) bpre[t] = s[t] - v;  // exclusive prefix
}

__global__ __launch_bounds__(256) void scan_final(const int* __restrict__ cnt,
                                                  const int* __restrict__ bpre,
                                                  int* __restrict__ offs,
                                                  int* __restrict__ cursor) {
    __shared__ int s[256];
    int t = threadIdx.x;
    int g = blockIdx.x * 256 + t;
    int v = cnt[g];
    s[t] = v;
    __syncthreads();
    for (int off = 1; off < 256; off <<= 1) {
        int u = (t >= off) ? s[t - off] : 0;
        __syncthreads();
        s[t] += u;
        __syncthreads();
    }
    int ex = bpre[blockIdx.x] + s[t] - v;
    offs[g] = ex;
    cursor[g] = ex;
    if (blockIdx.x == 0 && t == 0) offs[NSEG] = E_EDGES;
}

__global__ __launch_bounds__(256) void build_kernel(const int* __restrict__ src,
                                                    const int* __restrict__ dst,
                                                    const int* __restrict__ et,
                                                    int* __restrict__ cursor,
                                                    int* __restrict__ csr_src) {
    int e = blockIdx.x * 256 + threadIdx.x;
    if (e >= E_EDGES) return;
    int seg = dst[e] * RREL + et[e];
    int pos = atomicAdd(&cursor[seg], 1);
    csr_src[pos] = src[e];
}

// ---------------------------------------------------------------------------
// fp32 -> bf16 converts
// ---------------------------------------------------------------------------
__global__ __launch_bounds__(256) void convert_x(const float* __restrict__ x,
                                                 unsigned short* __restrict__ xb) {
    int i = blockIdx.x * 256 + threadIdx.x;           // one float4 each
    float4 v = ((const float4*)x)[i];
    unsigned int p0 = (unsigned int)f2bf(v.x) | ((unsigned int)f2bf(v.y) << 16);
    unsigned int p1 = (unsigned int)f2bf(v.z) | ((unsigned int)f2bf(v.w) << 16);
    ((uint2*)xb)[i] = make_uint2(p0, p1);
}

// wt[oc][k], oc in [0,128), k in [0,640):  k<512 -> w[k>>7][k&127][oc]
//                                          else  -> root[k-512][oc]
__global__ __launch_bounds__(256) void convert_w(const float* __restrict__ w1,
                                                 const float* __restrict__ r1,
                                                 const float* __restrict__ w2,
                                                 const float* __restrict__ r2,
                                                 unsigned short* __restrict__ wt1,
                                                 unsigned short* __restrict__ wt2) {
    int t = blockIdx.x * 256 + threadIdx.x;           // 0 .. 2*128*640-1
    int layer = (t >= FDIM * KTOT);
    int tl = layer ? t - FDIM * KTOT : t;
    int oc = tl / KTOT;
    int k  = tl - oc * KTOT;
    const float* w = layer ? w2 : w1;
    const float* r = layer ? r2 : r1;
    float v;
    if (k < KBIG)
        v = w[((size_t)(k >> 7) * FDIM + (k & 127)) * FDIM + oc];
    else
        v = r[(size_t)(k - KBIG) * FDIM + oc];
    (layer ? wt2 : wt1)[tl] = f2bf(v);
}

// ---------------------------------------------------------------------------
// Aggregate: accb[node*4+g][:] = mean over edges of segment (node,g) of xb[src].
// One wave per node; 16-lane group g owns relation g (no merge, no idle lanes).
// Each lane gathers 16B slices; x2 unrolled independent gathers for MLP.
// Wave writes 4 adjacent 256B rows = contiguous 1KB.
// ---------------------------------------------------------------------------
__global__ __launch_bounds__(256) void agg_kernel(
    const unsigned short* __restrict__ xb,
    const int* __restrict__ offs, const int* __restrict__ csr,
    unsigned short* __restrict__ accb) {
    const int node = blockIdx.x * 4 + (threadIdx.x >> 6);
    const int lane = threadIdx.x & 63;
    const int g  = lane >> 4;    // relation 0..3
    const int fl = lane & 15;    // features fl*8 .. fl*8+7
    const int seg = node * RREL + g;
    const int b = offs[seg], e = offs[seg + 1];

    float s[8];
#pragma unroll
    for (int j = 0; j < 8; ++j) s[j] = 0.f;

    int p = b;
    for (; p + 1 < e; p += 2) {
        int i0 = csr[p];
        int i1 = csr[p + 1];
        uint4 v0 = *(const uint4*)(xb + (size_t)i0 * FDIM + fl * 8);
        uint4 v1 = *(const uint4*)(xb + (size_t)i1 * FDIM + fl * 8);
        s[0] += bflo(v0.x); s[1] += bfhi(v0.x);
        s[2] += bflo(v0.y); s[3] += bfhi(v0.y);
        s[4] += bflo(v0.z); s[5] += bfhi(v0.z);
        s[6] += bflo(v0.w); s[7] += bfhi(v0.w);
        s[0] += bflo(v1.x); s[1] += bfhi(v1.x);
        s[2] += bflo(v1.y); s[3] += bfhi(v1.y);
        s[4] += bflo(v1.z); s[5] += bfhi(v1.z);
        s[6] += bflo(v1.w); s[7] += bfhi(v1.w);
    }
    if (p < e) {
        int i0 = csr[p];
        uint4 v0 = *(const uint4*)(xb + (size_t)i0 * FDIM + fl * 8);
        s[0] += bflo(v0.x); s[1] += bfhi(v0.x);
        s[2] += bflo(v0.y); s[3] += bfhi(v0.y);
        s[4] += bflo(v0.z); s[5] += bfhi(v0.z);
        s[6] += bflo(v0.w); s[7] += bfhi(v0.w);
    }
    float rcp = 1.0f / (float)max(e - b, 1);
    uint4 pk;
    pk.x = (unsigned int)f2bf(s[0] * rcp) | ((unsigned int)f2bf(s[1] * rcp) << 16);
    pk.y = (unsigned int)f2bf(s[2] * rcp) | ((unsigned int)f2bf(s[3] * rcp) << 16);
    pk.z = (unsigned int)f2bf(s[4] * rcp) | ((unsigned int)f2bf(s[5] * rcp) << 16);
    pk.w = (unsigned int)f2bf(s[6] * rcp) | ((unsigned int)f2bf(s[7] * rcp) << 16);
    *(uint4*)(accb + (size_t)seg * FDIM + fl * 8) = pk;
}

// ---------------------------------------------------------------------------
// MFMA GEMM (K=640): out[n,:] = [accb(n,:) | xh(n,:)] @ wt^T + bias
// wt is [128 oc][640 k] bf16. Block 64 rows x 128 cols, 4 waves (2x2),
// K-loop 5 x BK=128. Fragment-linear LDS: all ds ops base + lane*16B.
// Epilogue fuses bias (+ReLU) and bf16/fp32 output.
// ---------------------------------------------------------------------------
template <int RELU, int OUT_BF16>
__global__ __launch_bounds__(256) void gemm_k640(
    const unsigned short* __restrict__ accb,  // [N][512] bf16
    const unsigned short* __restrict__ xh,    // [N][128] bf16
    const unsigned short* __restrict__ wt,    // [128][640] bf16
    const float* __restrict__ bias,
    unsigned short* __restrict__ hout, float* __restrict__ fout) {
    __shared__ unsigned short sA[16 * 512];   // 64 rows x 128 k
    __shared__ unsigned short sB[32 * 512];   // 128 oc x 128 k

    const int tid = threadIdx.x;
    const int wid = tid >> 6, lane = tid & 63;
    const int lrow = lane & 15, lk8 = lane >> 4;
    const int row0 = blockIdx.x * 64;
    const int wr = wid >> 1, wc = wid & 1;

    f32x4 acc[2][4];
#pragma unroll
    for (int i = 0; i < 2; ++i)
#pragma unroll
        for (int j = 0; j < 4; ++j) acc[i][j] = (f32x4){0.f, 0.f, 0.f, 0.f};

    for (int ks = 0; ks < 5; ++ks) {
        const int kb = ks * 128;
        // stage 48KB: 12 frag-blocks per wave, 16B per lane each
#pragma unroll
        for (int it = 0; it < 12; ++it) {
            int bid = wid * 12 + it;
            const unsigned short* gp;
            unsigned short* lp;
            if (bid < 16) {                   // A blocks (mt, kt)
                int mt = bid >> 2, kt = bid & 3;
                int row = row0 + mt * 16 + lrow;
                int kk = kt * 32 + lk8 * 8;
                gp = (ks < 4) ? accb + (size_t)row * KBIG + kb + kk
                              : xh + (size_t)row * FDIM + kk;
                lp = &sA[bid * 512 + lane * 8];
            } else {                          // B blocks (nt, kt)
                int b = bid - 16, nt = b >> 2, kt = b & 3;
                gp = wt + (size_t)(nt * 16 + lrow) * KTOT + kb + kt * 32 + lk8 * 8;
                lp = &sB[b * 512 + lane * 8];
            }
            *(uint4*)lp = *(const uint4*)gp;
        }
        __syncthreads();

#pragma unroll
        for (int kt = 0; kt < 4; ++kt) {
            s16x8 a[2], b[4];
#pragma unroll
            for (int i = 0; i < 2; ++i)
                a[i] = *(const s16x8*)&sA[(((wr * 2 + i) * 4) + kt) * 512 + lane * 8];
#pragma unroll
            for (int j = 0; j < 4; ++j)
                b[j] = *(const s16x8*)&sB[(((wc * 4 + j) * 4) + kt) * 512 + lane * 8];
#pragma unroll
            for (int i = 0; i < 2; ++i)
#pragma unroll
                for (int j = 0; j < 4; ++j)
                    acc[i][j] = __builtin_amdgcn_mfma_f32_16x16x32_bf16(a[i], b[j], acc[i][j], 0, 0, 0);
        }
        __syncthreads();
    }

    // epilogue: C/D layout col=lane&15, row=(lane>>4)*4+reg  [m89-verified]
    float bb[4];
#pragma unroll
    for (int j = 0; j < 4; ++j) bb[j] = bias[wc * 64 + j * 16 + lrow];
#pragma unroll
    for (int i = 0; i < 2; ++i)
#pragma unroll
        for (int j = 0; j < 4; ++j)
#pragma unroll
            for (int q = 0; q < 4; ++q) {
                int row = row0 + wr * 32 + i * 16 + lk8 * 4 + q;
                int col = wc * 64 + j * 16 + lrow;
                float v = acc[i][j][q] + bb[j];
                if (RELU) v = fmaxf(v, 0.f);
                if (OUT_BF16) hout[(size_t)row * FDIM + col] = f2bf(v);
                else          fout[(size_t)row * FDIM + col] = v;
            }
}

extern "C" void kernel_launch(void* const* d_in, const int* in_sizes, int n_in,
                              void* d_out, int out_size, void* d_ws, size_t ws_size,
                              hipStream_t stream) {
    const float* x     = (const float*)d_in[0];
    const float* w1    = (const float*)d_in[1];
    const float* root1 = (const float*)d_in[2];
    const float* b1    = (const float*)d_in[3];
    const float* w2    = (const float*)d_in[4];
    const float* root2 = (const float*)d_in[5];
    const float* b2    = (const float*)d_in[6];
    const int*   ei    = (const int*)d_in[7];   // [2, E]
    const int*   et    = (const int*)d_in[8];   // [E]
    float* out = (float*)d_out;

    const int* srcv = ei;
    const int* dstv = ei + E_EDGES;

    // ---- workspace layout ----
    size_t io = 0;
    int* cnt_i  = (int*)d_ws + io;  io += NSEG;
    int* offs   = (int*)d_ws + io;  io += NSEG + 1;
    int* cursor = (int*)d_ws + io;  io += NSEG;
    int* csr    = (int*)d_ws + io;  io += E_EDGES;
    int* bsum   = (int*)d_ws + io;  io += SCAN_BLOCKS;
    int* bpre   = (int*)d_ws + io;  io += SCAN_BLOCKS;
    io = (io + 63) & ~(size_t)63;                       // 256B-align
    unsigned short* us  = (unsigned short*)((int*)d_ws + io);
    size_t uo = 0;
    unsigned short* xb   = us + uo;  uo += (size_t)N_NODES * FDIM;  // bf16 x
    unsigned short* wt1  = us + uo;  uo += (size_t)FDIM * KTOT;     // bf16 W1^T
    unsigned short* wt2  = us + uo;  uo += (size_t)FDIM * KTOT;     // bf16 W2^T
    unsigned short* h    = us + uo;  uo += (size_t)N_NODES * FDIM;  // bf16 hidden
    unsigned short* accb = us + uo;  uo += (size_t)NSEG * FDIM;     // bf16 means

    const int eb = (E_EDGES + 255) / 256;      // 2500

    // ---- build CSR once (reused by both layers) ----
    fill_zero<<<SCAN_BLOCKS, 256, 0, stream>>>(cnt_i);
    hist_kernel<<<eb, 256, 0, stream>>>(dstv, et, cnt_i);
    scan_part<<<SCAN_BLOCKS, 256, 0, stream>>>(cnt_i, bsum);
    scan_mid<<<1, 1024, 0, stream>>>(bsum, bpre);
    scan_final<<<SCAN_BLOCKS, 256, 0, stream>>>(cnt_i, bpre, offs, cursor);
    build_kernel<<<eb, 256, 0, stream>>>(srcv, dstv, et, cursor, csr);

    // ---- converts ----
    convert_x<<<(N_NODES * FDIM / 4) / 256, 256, 0, stream>>>(x, xb);
    convert_w<<<(2 * FDIM * KTOT) / 256, 256, 0, stream>>>(w1, root1, w2, root2, wt1, wt2);

    // ---- layer 1: agg(x) -> accb; h = relu([accb|x] @ Wt1 + b1) ----
    agg_kernel<<<N_NODES / 4, 256, 0, stream>>>(xb, offs, csr, accb);
    gemm_k640<1, 1><<<N_NODES / 64, 256, 0, stream>>>(accb, xb, wt1, b1, h, nullptr);

    // ---- layer 2: agg(h) -> accb; out = [accb|h] @ Wt2 + b2 ----
    agg_kernel<<<N_NODES / 4, 256, 0, stream>>>(h, offs, csr, accb);
    gemm_k640<0, 0><<<N_NODES / 64, 256, 0, stream>>>(accb, h, wt2, b2, nullptr, out);
}

// Round 7
// 190.949 us; speedup vs baseline: 16.2275x; 1.0763x over previous
//
#include <hip/hip_runtime.h>

#define N_NODES 40000
#define E_EDGES 640000
#define FDIM 128
#define RREL 4
#define NSEG (N_NODES * RREL)        // 160000
#define KBIG (RREL * FDIM)           // 512
#define KTOT (KBIG + FDIM)           // 640
#define SCAN_BLOCKS 625              // NSEG / 256

typedef __attribute__((ext_vector_type(8))) short s16x8;
typedef __attribute__((ext_vector_type(4))) float f32x4;

__device__ __forceinline__ unsigned short f2bf(float f) {
    unsigned int b = __float_as_uint(f);
    b = (b + 0x7FFFu + ((b >> 16) & 1u)) >> 16;   // round-to-nearest-even
    return (unsigned short)b;
}
__device__ __forceinline__ float bflo(unsigned int v) { return __uint_as_float(v << 16); }
__device__ __forceinline__ float bfhi(unsigned int v) { return __uint_as_float(v & 0xFFFF0000u); }

// async global->LDS, 16B per lane; LDS dest must be wave-uniform base + lane*16
__device__ __forceinline__ void async_copy16(const void* gsrc, void* ldst) {
    __builtin_amdgcn_global_load_lds(
        (const __attribute__((address_space(1))) void*)gsrc,
        (__attribute__((address_space(3))) void*)ldst, 16, 0, 0);
}

// ---------------------------------------------------------------------------
// Fused setup: zero cnt | convert x -> bf16 | convert+transpose weights
// blocks [0,625): fill; [625,5625): convert_x; [5625,6265): convert_w
// ---------------------------------------------------------------------------
__global__ __launch_bounds__(256) void setup_kernel(
    const float* __restrict__ x,
    const float* __restrict__ w1, const float* __restrict__ r1,
    const float* __restrict__ w2, const float* __restrict__ r2,
    int* __restrict__ cnt, unsigned short* __restrict__ xb,
    unsigned short* __restrict__ wt1, unsigned short* __restrict__ wt2) {
    const int bid = blockIdx.x;
    const int t = threadIdx.x;
    if (bid < SCAN_BLOCKS) {
        cnt[bid * 256 + t] = 0;
    } else if (bid < SCAN_BLOCKS + 5000) {
        int i = (bid - SCAN_BLOCKS) * 256 + t;        // one float4 each
        float4 v = ((const float4*)x)[i];
        unsigned int p0 = (unsigned int)f2bf(v.x) | ((unsigned int)f2bf(v.y) << 16);
        unsigned int p1 = (unsigned int)f2bf(v.z) | ((unsigned int)f2bf(v.w) << 16);
        ((uint2*)xb)[i] = make_uint2(p0, p1);
    } else {
        int tl = (bid - SCAN_BLOCKS - 5000) * 256 + t;   // 0 .. 2*128*640-1
        int layer = (tl >= FDIM * KTOT);
        if (layer) tl -= FDIM * KTOT;
        int oc = tl / KTOT;
        int k  = tl - oc * KTOT;
        const float* w = layer ? w2 : w1;
        const float* r = layer ? r2 : r1;
        float v;
        if (k < KBIG)
            v = w[((size_t)(k >> 7) * FDIM + (k & 127)) * FDIM + oc];
        else
            v = r[(size_t)(k - KBIG) * FDIM + oc];
        (layer ? wt2 : wt1)[(size_t)oc * KTOT + k] = f2bf(v);
    }
}

// ---------------------------------------------------------------------------
// CSR build: histogram -> 3-pass scan -> slot scatter (seg = dst*R + rel)
// ---------------------------------------------------------------------------
__global__ __launch_bounds__(256) void hist_kernel(const int* __restrict__ dst,
                                                   const int* __restrict__ et,
                                                   int* __restrict__ cnt) {
    int e = blockIdx.x * 256 + threadIdx.x;
    if (e >= E_EDGES) return;
    atomicAdd(&cnt[dst[e] * RREL + et[e]], 1);
}

__global__ __launch_bounds__(256) void scan_part(const int* __restrict__ cnt,
                                                 int* __restrict__ bsum) {
    __shared__ int s[256];
    int t = threadIdx.x;
    s[t] = cnt[blockIdx.x * 256 + t];
    __syncthreads();
#pragma unroll
    for (int off = 128; off > 0; off >>= 1) {
        if (t < off) s[t] += s[t + off];
        __syncthreads();
    }
    if (t == 0) bsum[blockIdx.x] = s[0];
}

__global__ __launch_bounds__(1024) void scan_mid(const int* __restrict__ bsum,
                                                 int* __restrict__ bpre) {
    __shared__ int s[1024];
    int t = threadIdx.x;
    int v = (t < SCAN_BLOCKS) ? bsum[t] : 0;
    s[t] = v;
    __syncthreads();
    for (int off = 1; off < 1024; off <<= 1) {
        int u = (t >= off) ? s[t - off] : 0;
        __syncthreads();
        s[t] += u;
        __syncthreads();
    }
    if (t < SCAN_BLOCKS) bpre[t] = s[t] - v;  // exclusive prefix
}

__global__ __launch_bounds__(256) void scan_final(const int* __restrict__ cnt,
                                                  const int* __restrict__ bpre,
                                                  int* __restrict__ offs,
                                                  int* __restrict__ cursor) {
    __shared__ int s[256];
    int t = threadIdx.x;
    int g = blockIdx.x * 256 + t;
    int v = cnt[g];
    s[t] = v;
    __syncthreads();
    for (int off = 1; off < 256; off <<= 1) {
        int u = (t >= off) ? s[t - off] : 0;
        __syncthreads();
        s[t] += u;
        __syncthreads();
    }
    int ex = bpre[blockIdx.x] + s[t] - v;
    offs[g] = ex;
    cursor[g] = ex;
    if (blockIdx.x == 0 && t == 0) offs[NSEG] = E_EDGES;
}

__global__ __launch_bounds__(256) void build_kernel(const int* __restrict__ src,
                                                    const int* __restrict__ dst,
                                                    const int* __restrict__ et,
                                                    int* __restrict__ cursor,
                                                    int* __restrict__ csr_src) {
    int e = blockIdx.x * 256 + threadIdx.x;
    if (e >= E_EDGES) return;
    int seg = dst[e] * RREL + et[e];
    int pos = atomicAdd(&cursor[seg], 1);
    csr_src[pos] = src[e];
}

// ---------------------------------------------------------------------------
// Aggregate: accb[node*4+g][:] = mean over edges of segment (node,g) of xb[src].
// One wave per node; 16-lane group g owns relation g. 16B/lane gathers,
// 4 independent loads in flight.
// ---------------------------------------------------------------------------
__global__ __launch_bounds__(256) void agg_kernel(
    const unsigned short* __restrict__ xb,
    const int* __restrict__ offs, const int* __restrict__ csr,
    unsigned short* __restrict__ accb) {
    const int node = blockIdx.x * 4 + (threadIdx.x >> 6);
    const int lane = threadIdx.x & 63;
    const int g  = lane >> 4;    // relation 0..3
    const int fl = lane & 15;    // features fl*8 .. fl*8+7
    const int seg = node * RREL + g;
    const int b = offs[seg], e = offs[seg + 1];
    const unsigned short* xf = xb + fl * 8;

    float s[8];
#pragma unroll
    for (int j = 0; j < 8; ++j) s[j] = 0.f;

    int p = b;
    for (; p + 3 < e; p += 4) {
        int i0 = csr[p], i1 = csr[p + 1], i2 = csr[p + 2], i3 = csr[p + 3];
        uint4 v0 = *(const uint4*)(xf + (size_t)i0 * FDIM);
        uint4 v1 = *(const uint4*)(xf + (size_t)i1 * FDIM);
        uint4 v2 = *(const uint4*)(xf + (size_t)i2 * FDIM);
        uint4 v3 = *(const uint4*)(xf + (size_t)i3 * FDIM);
        s[0] += bflo(v0.x) + bflo(v1.x) + bflo(v2.x) + bflo(v3.x);
        s[1] += bfhi(v0.x) + bfhi(v1.x) + bfhi(v2.x) + bfhi(v3.x);
        s[2] += bflo(v0.y) + bflo(v1.y) + bflo(v2.y) + bflo(v3.y);
        s[3] += bfhi(v0.y) + bfhi(v1.y) + bfhi(v2.y) + bfhi(v3.y);
        s[4] += bflo(v0.z) + bflo(v1.z) + bflo(v2.z) + bflo(v3.z);
        s[5] += bfhi(v0.z) + bfhi(v1.z) + bfhi(v2.z) + bfhi(v3.z);
        s[6] += bflo(v0.w) + bflo(v1.w) + bflo(v2.w) + bflo(v3.w);
        s[7] += bfhi(v0.w) + bfhi(v1.w) + bfhi(v2.w) + bfhi(v3.w);
    }
    for (; p < e; ++p) {
        int i0 = csr[p];
        uint4 v0 = *(const uint4*)(xf + (size_t)i0 * FDIM);
        s[0] += bflo(v0.x); s[1] += bfhi(v0.x);
        s[2] += bflo(v0.y); s[3] += bfhi(v0.y);
        s[4] += bflo(v0.z); s[5] += bfhi(v0.z);
        s[6] += bflo(v0.w); s[7] += bfhi(v0.w);
    }
    float rcp = 1.0f / (float)max(e - b, 1);
    uint4 pk;
    pk.x = (unsigned int)f2bf(s[0] * rcp) | ((unsigned int)f2bf(s[1] * rcp) << 16);
    pk.y = (unsigned int)f2bf(s[2] * rcp) | ((unsigned int)f2bf(s[3] * rcp) << 16);
    pk.z = (unsigned int)f2bf(s[4] * rcp) | ((unsigned int)f2bf(s[5] * rcp) << 16);
    pk.w = (unsigned int)f2bf(s[6] * rcp) | ((unsigned int)f2bf(s[7] * rcp) << 16);
    *(uint4*)(accb + (size_t)seg * FDIM + fl * 8) = pk;
}

// ---------------------------------------------------------------------------
// MFMA GEMM (K=640): out[n,:] = [accb(n,:) | xh(n,:)] @ wt^T + bias
// wt is [128 oc][640 k] bf16. Block 64 rows x 128 cols, 4 waves (2x2),
// K-loop 5 x BK=128. Staging via async global_load_lds (16B/lane, LDS dest
// = wave-uniform base + lane*16 -> fragment-linear layout is exactly right).
// ---------------------------------------------------------------------------
template <int RELU, int OUT_BF16>
__global__ __launch_bounds__(256) void gemm_k640(
    const unsigned short* __restrict__ accb,  // [N][512] bf16
    const unsigned short* __restrict__ xh,    // [N][128] bf16
    const unsigned short* __restrict__ wt,    // [128][640] bf16
    const float* __restrict__ bias,
    unsigned short* __restrict__ hout, float* __restrict__ fout) {
    __shared__ unsigned short sA[16 * 512];   // 64 rows x 128 k
    __shared__ unsigned short sB[32 * 512];   // 128 oc x 128 k

    const int tid = threadIdx.x;
    const int wid = tid >> 6, lane = tid & 63;
    const int lrow = lane & 15, lk8 = lane >> 4;
    const int row0 = blockIdx.x * 64;
    const int wr = wid >> 1, wc = wid & 1;

    f32x4 acc[2][4];
#pragma unroll
    for (int i = 0; i < 2; ++i)
#pragma unroll
        for (int j = 0; j < 4; ++j) acc[i][j] = (f32x4){0.f, 0.f, 0.f, 0.f};

    for (int ks = 0; ks < 5; ++ks) {
        const int kb = ks * 128;
        // stage 48KB async: 12 frag-blocks per wave, 16B per lane each
#pragma unroll
        for (int it = 0; it < 12; ++it) {
            int bid = wid * 12 + it;
            if (bid < 16) {                   // A blocks (mt, kt)
                int mt = bid >> 2, kt = bid & 3;
                int row = row0 + mt * 16 + lrow;
                int kk = kt * 32 + lk8 * 8;
                const unsigned short* gp = (ks < 4)
                    ? accb + (size_t)row * KBIG + kb + kk
                    : xh + (size_t)row * FDIM + kk;
                async_copy16(gp, &sA[bid * 512]);
            } else {                          // B blocks (nt, kt)
                int b = bid - 16, nt = b >> 2, kt = b & 3;
                const unsigned short* gp =
                    wt + (size_t)(nt * 16 + lrow) * KTOT + kb + kt * 32 + lk8 * 8;
                async_copy16(gp, &sB[b * 512]);
            }
        }
        __syncthreads();

#pragma unroll
        for (int kt = 0; kt < 4; ++kt) {
            s16x8 a[2], b[4];
#pragma unroll
            for (int i = 0; i < 2; ++i)
                a[i] = *(const s16x8*)&sA[(((wr * 2 + i) * 4) + kt) * 512 + lane * 8];
#pragma unroll
            for (int j = 0; j < 4; ++j)
                b[j] = *(const s16x8*)&sB[(((wc * 4 + j) * 4) + kt) * 512 + lane * 8];
#pragma unroll
            for (int i = 0; i < 2; ++i)
#pragma unroll
                for (int j = 0; j < 4; ++j)
                    acc[i][j] = __builtin_amdgcn_mfma_f32_16x16x32_bf16(a[i], b[j], acc[i][j], 0, 0, 0);
        }
        __syncthreads();
    }

    // epilogue: C/D layout col=lane&15, row=(lane>>4)*4+reg  [m89-verified]
    float bb[4];
#pragma unroll
    for (int j = 0; j < 4; ++j) bb[j] = bias[wc * 64 + j * 16 + lrow];
#pragma unroll
    for (int i = 0; i < 2; ++i)
#pragma unroll
        for (int j = 0; j < 4; ++j)
#pragma unroll
            for (int q = 0; q < 4; ++q) {
                int row = row0 + wr * 32 + i * 16 + lk8 * 4 + q;
                int col = wc * 64 + j * 16 + lrow;
                float v = acc[i][j][q] + bb[j];
                if (RELU) v = fmaxf(v, 0.f);
                if (OUT_BF16) hout[(size_t)row * FDIM + col] = f2bf(v);
                else          fout[(size_t)row * FDIM + col] = v;
            }
}

extern "C" void kernel_launch(void* const* d_in, const int* in_sizes, int n_in,
                              void* d_out, int out_size, void* d_ws, size_t ws_size,
                              hipStream_t stream) {
    const float* x     = (const float*)d_in[0];
    const float* w1    = (const float*)d_in[1];
    const float* root1 = (const float*)d_in[2];
    const float* b1    = (const float*)d_in[3];
    const float* w2    = (const float*)d_in[4];
    const float* root2 = (const float*)d_in[5];
    const float* b2    = (const float*)d_in[6];
    const int*   ei    = (const int*)d_in[7];   // [2, E]
    const int*   et    = (const int*)d_in[8];   // [E]
    float* out = (float*)d_out;

    const int* srcv = ei;
    const int* dstv = ei + E_EDGES;

    // ---- workspace layout ----
    size_t io = 0;
    int* cnt_i  = (int*)d_ws + io;  io += NSEG;
    int* offs   = (int*)d_ws + io;  io += NSEG + 1;
    int* cursor = (int*)d_ws + io;  io += NSEG;
    int* csr    = (int*)d_ws + io;  io += E_EDGES;
    int* bsum   = (int*)d_ws + io;  io += SCAN_BLOCKS;
    int* bpre   = (int*)d_ws + io;  io += SCAN_BLOCKS;
    io = (io + 63) & ~(size_t)63;                       // 256B-align
    unsigned short* us  = (unsigned short*)((int*)d_ws + io);
    size_t uo = 0;
    unsigned short* xb   = us + uo;  uo += (size_t)N_NODES * FDIM;  // bf16 x
    unsigned short* wt1  = us + uo;  uo += (size_t)FDIM * KTOT;     // bf16 W1^T
    unsigned short* wt2  = us + uo;  uo += (size_t)FDIM * KTOT;     // bf16 W2^T
    unsigned short* h    = us + uo;  uo += (size_t)N_NODES * FDIM;  // bf16 hidden
    unsigned short* accb = us + uo;  uo += (size_t)NSEG * FDIM;     // bf16 means

    const int eb = (E_EDGES + 255) / 256;      // 2500

    // ---- setup (zero cnt + bf16 converts, fused) ----
    setup_kernel<<<SCAN_BLOCKS + 5000 + 640, 256, 0, stream>>>(
        x, w1, root1, w2, root2, cnt_i, xb, wt1, wt2);

    // ---- build CSR once (reused by both layers) ----
    hist_kernel<<<eb, 256, 0, stream>>>(dstv, et, cnt_i);
    scan_part<<<SCAN_BLOCKS, 256, 0, stream>>>(cnt_i, bsum);
    scan_mid<<<1, 1024, 0, stream>>>(bsum, bpre);
    scan_final<<<SCAN_BLOCKS, 256, 0, stream>>>(cnt_i, bpre, offs, cursor);
    build_kernel<<<eb, 256, 0, stream>>>(srcv, dstv, et, cursor, csr);

    // ---- layer 1: agg(x) -> accb; h = relu([accb|x] @ Wt1 + b1) ----
    agg_kernel<<<N_NODES / 4, 256, 0, stream>>>(xb, offs, csr, accb);
    gemm_k640<1, 1><<<N_NODES / 64, 256, 0, stream>>>(accb, xb, wt1, b1, h, nullptr);

    // ---- layer 2: agg(h) -> accb; out = [accb|h] @ Wt2 + b2 ----
    agg_kernel<<<N_NODES / 4, 256, 0, stream>>>(h, offs, csr, accb);
    gemm_k640<0, 0><<<N_NODES / 64, 256, 0, stream>>>(accb, h, wt2, b2, nullptr, out);
}

// Round 8
// 187.430 us; speedup vs baseline: 16.5322x; 1.0188x over previous
//
#include <hip/hip_runtime.h>

#define N_NODES 40000
#define E_EDGES 640000
#define FDIM 128
#define RREL 4
#define NSEG (N_NODES * RREL)        // 160000
#define KBIG (RREL * FDIM)           // 512
#define KTOT (KBIG + FDIM)           // 640
#define SCAN_BLOCKS 625              // NSEG / 256
#define CSR_PAD (E_EDGES + 3 * NSEG) // 1120000 worst-case padded slots

typedef __attribute__((ext_vector_type(8))) short s16x8;
typedef __attribute__((ext_vector_type(4))) float f32x4;

__device__ __forceinline__ unsigned short f2bf(float f) {
    unsigned int b = __float_as_uint(f);
    b = (b + 0x7FFFu + ((b >> 16) & 1u)) >> 16;   // round-to-nearest-even
    return (unsigned short)b;
}
__device__ __forceinline__ float bflo(unsigned int v) { return __uint_as_float(v << 16); }
__device__ __forceinline__ float bfhi(unsigned int v) { return __uint_as_float(v & 0xFFFF0000u); }

// async global->LDS, 16B per lane; LDS dest must be wave-uniform base + lane*16
__device__ __forceinline__ void async_copy16(const void* gsrc, void* ldst) {
    __builtin_amdgcn_global_load_lds(
        (const __attribute__((address_space(1))) void*)gsrc,
        (__attribute__((address_space(3))) void*)ldst, 16, 0, 0);
}

// ---------------------------------------------------------------------------
// Fused setup: zero cnt | convert x->bf16 | convert+transpose weights |
//              fill csr with dummy idx | zero dummy rows of xb,h
// ---------------------------------------------------------------------------
#define SB_CNT 625
#define SB_CX  5000
#define SB_CW  640
#define SB_CF  4375   // CSR_PAD / 256

__global__ __launch_bounds__(256) void setup_kernel(
    const float* __restrict__ x,
    const float* __restrict__ w1, const float* __restrict__ r1,
    const float* __restrict__ w2, const float* __restrict__ r2,
    int* __restrict__ cnt, unsigned short* __restrict__ xb,
    unsigned short* __restrict__ wt1, unsigned short* __restrict__ wt2,
    int* __restrict__ csr, unsigned short* __restrict__ h) {
    const int bid = blockIdx.x;
    const int t = threadIdx.x;
    if (bid < SB_CNT) {
        cnt[bid * 256 + t] = 0;
    } else if (bid < SB_CNT + SB_CX) {
        int i = (bid - SB_CNT) * 256 + t;             // one float4 each
        float4 v = ((const float4*)x)[i];
        unsigned int p0 = (unsigned int)f2bf(v.x) | ((unsigned int)f2bf(v.y) << 16);
        unsigned int p1 = (unsigned int)f2bf(v.z) | ((unsigned int)f2bf(v.w) << 16);
        ((uint2*)xb)[i] = make_uint2(p0, p1);
    } else if (bid < SB_CNT + SB_CX + SB_CW) {
        int tl = (bid - SB_CNT - SB_CX) * 256 + t;    // 0 .. 2*128*640-1
        int layer = (tl >= FDIM * KTOT);
        if (layer) tl -= FDIM * KTOT;
        int oc = tl / KTOT;
        int k  = tl - oc * KTOT;
        const float* w = layer ? w2 : w1;
        const float* r = layer ? r2 : r1;
        float v;
        if (k < KBIG)
            v = w[((size_t)(k >> 7) * FDIM + (k & 127)) * FDIM + oc];
        else
            v = r[(size_t)(k - KBIG) * FDIM + oc];
        (layer ? wt2 : wt1)[(size_t)oc * KTOT + k] = f2bf(v);
    } else if (bid < SB_CNT + SB_CX + SB_CW + SB_CF) {
        int i = (bid - SB_CNT - SB_CX - SB_CW) * 256 + t;
        csr[i] = N_NODES;                             // dummy -> zero row
    } else {
        // zero the dummy rows xb[N] and h[N] (64 uints each)
        if (t < 64)        ((unsigned int*)(xb + (size_t)N_NODES * FDIM))[t] = 0;
        else if (t < 128)  ((unsigned int*)(h  + (size_t)N_NODES * FDIM))[t - 64] = 0;
    }
}

// ---------------------------------------------------------------------------
// CSR build: histogram -> 3-pass scan (PADDED to x4) -> slot scatter
// ---------------------------------------------------------------------------
__global__ __launch_bounds__(256) void hist_kernel(const int* __restrict__ dst,
                                                   const int* __restrict__ et,
                                                   int* __restrict__ cnt) {
    int e = blockIdx.x * 256 + threadIdx.x;
    if (e >= E_EDGES) return;
    atomicAdd(&cnt[dst[e] * RREL + et[e]], 1);
}

__global__ __launch_bounds__(256) void scan_part(const int* __restrict__ cnt,
                                                 int* __restrict__ bsum) {
    __shared__ int s[256];
    int t = threadIdx.x;
    s[t] = (cnt[blockIdx.x * 256 + t] + 3) & ~3;      // padded count
    __syncthreads();
#pragma unroll
    for (int off = 128; off > 0; off >>= 1) {
        if (t < off) s[t] += s[t + off];
        __syncthreads();
    }
    if (t == 0) bsum[blockIdx.x] = s[0];
}

__global__ __launch_bounds__(1024) void scan_mid(const int* __restrict__ bsum,
                                                 int* __restrict__ bpre) {
    __shared__ int s[1024];
    int t = threadIdx.x;
    int v = (t < SCAN_BLOCKS) ? bsum[t] : 0;
    s[t] = v;
    __syncthreads();
    for (int off = 1; off < 1024; off <<= 1) {
        int u = (t >= off) ? s[t - off] : 0;
        __syncthreads();
        s[t] += u;
        __syncthreads();
    }
    if (t < SCAN_BLOCKS) bpre[t] = s[t] - v;  // exclusive prefix
}

__global__ __launch_bounds__(256) void scan_final(const int* __restrict__ cnt,
                                                  const int* __restrict__ bpre,
                                                  int* __restrict__ offs,
                                                  int* __restrict__ cursor) {
    __shared__ int s[256];
    int t = threadIdx.x;
    int g = blockIdx.x * 256 + t;
    int pv = (cnt[g] + 3) & ~3;                       // padded count
    s[t] = pv;
    __syncthreads();
    for (int off = 1; off < 256; off <<= 1) {
        int u = (t >= off) ? s[t - off] : 0;
        __syncthreads();
        s[t] += u;
        __syncthreads();
    }
    int ex = bpre[blockIdx.x] + s[t] - pv;
    offs[g] = ex;
    cursor[g] = ex;
    if (g == NSEG - 1) offs[NSEG] = ex + pv;          // padded grand total
}

__global__ __launch_bounds__(256) void build_kernel(const int* __restrict__ src,
                                                    const int* __restrict__ dst,
                                                    const int* __restrict__ et,
                                                    int* __restrict__ cursor,
                                                    int* __restrict__ csr_src) {
    int e = blockIdx.x * 256 + threadIdx.x;
    if (e >= E_EDGES) return;
    int seg = dst[e] * RREL + et[e];
    int pos = atomicAdd(&cursor[seg], 1);
    csr_src[pos] = src[e];
}

// ---------------------------------------------------------------------------
// Aggregate: accb[seg][:] = (1/cnt) * sum of xb[src] over padded edge slots.
// Segments padded to x4: tail-free loop, aligned int4 index loads,
// 4 independent 16B gathers in flight; dummy slots hit the zero row.
// ---------------------------------------------------------------------------
__global__ __launch_bounds__(256) void agg_kernel(
    const unsigned short* __restrict__ xb,
    const int* __restrict__ offs, const int* __restrict__ cnt_i,
    const int* __restrict__ csr,
    unsigned short* __restrict__ accb) {
    const int node = blockIdx.x * 4 + (threadIdx.x >> 6);
    const int lane = threadIdx.x & 63;
    const int g  = lane >> 4;    // relation 0..3
    const int fl = lane & 15;    // features fl*8 .. fl*8+7
    const int seg = node * RREL + g;
    const int b = offs[seg], e = offs[seg + 1];
    const unsigned short* xf = xb + fl * 8;

    float s[8];
#pragma unroll
    for (int j = 0; j < 8; ++j) s[j] = 0.f;

    for (int p = b; p < e; p += 4) {
        int4 idx = *(const int4*)(csr + p);
        uint4 v0 = *(const uint4*)(xf + (size_t)idx.x * FDIM);
        uint4 v1 = *(const uint4*)(xf + (size_t)idx.y * FDIM);
        uint4 v2 = *(const uint4*)(xf + (size_t)idx.z * FDIM);
        uint4 v3 = *(const uint4*)(xf + (size_t)idx.w * FDIM);
        s[0] += bflo(v0.x) + bflo(v1.x) + bflo(v2.x) + bflo(v3.x);
        s[1] += bfhi(v0.x) + bfhi(v1.x) + bfhi(v2.x) + bfhi(v3.x);
        s[2] += bflo(v0.y) + bflo(v1.y) + bflo(v2.y) + bflo(v3.y);
        s[3] += bfhi(v0.y) + bfhi(v1.y) + bfhi(v2.y) + bfhi(v3.y);
        s[4] += bflo(v0.z) + bflo(v1.z) + bflo(v2.z) + bflo(v3.z);
        s[5] += bfhi(v0.z) + bfhi(v1.z) + bfhi(v2.z) + bfhi(v3.z);
        s[6] += bflo(v0.w) + bflo(v1.w) + bflo(v2.w) + bflo(v3.w);
        s[7] += bfhi(v0.w) + bfhi(v1.w) + bfhi(v2.w) + bfhi(v3.w);
    }
    float rcp = 1.0f / (float)max(cnt_i[seg], 1);
    uint4 pk;
    pk.x = (unsigned int)f2bf(s[0] * rcp) | ((unsigned int)f2bf(s[1] * rcp) << 16);
    pk.y = (unsigned int)f2bf(s[2] * rcp) | ((unsigned int)f2bf(s[3] * rcp) << 16);
    pk.z = (unsigned int)f2bf(s[4] * rcp) | ((unsigned int)f2bf(s[5] * rcp) << 16);
    pk.w = (unsigned int)f2bf(s[6] * rcp) | ((unsigned int)f2bf(s[7] * rcp) << 16);
    *(uint4*)(accb + (size_t)seg * FDIM + fl * 8) = pk;
}

// ---------------------------------------------------------------------------
// MFMA GEMM (K=640): out[n,:] = [accb(n,:) | xh(n,:)] @ wt^T + bias
// Double-buffered BK=64 pipeline: STAGE(t+1) issued BEFORE compute(t);
// counted s_waitcnt vmcnt(6) keeps next chunk's 6 global_load_lds in flight;
// raw s_barrier (NOT __syncthreads -> would drain vmcnt(0)).
// LDS 2 x (8KB A + 16KB B) = 48KB -> 3 blocks/CU.
// ---------------------------------------------------------------------------
template <int RELU, int OUT_BF16>
__global__ __launch_bounds__(256) void gemm_k640(
    const unsigned short* __restrict__ accb,  // [N][512] bf16
    const unsigned short* __restrict__ xh,    // [N][128] bf16
    const unsigned short* __restrict__ wt,    // [128][640] bf16
    const float* __restrict__ bias,
    unsigned short* __restrict__ hout, float* __restrict__ fout) {
    __shared__ unsigned short sA[2][8 * 512];   // [buf][mt*2+kt2][lane*8]
    __shared__ unsigned short sB[2][16 * 512];  // [buf][nt*2+kt2][lane*8]

    const int tid = threadIdx.x;
    const int wid = tid >> 6, lane = tid & 63;
    const int lrow = lane & 15, lk8 = lane >> 4;
    const int row0 = blockIdx.x * 64;
    const int wr = wid >> 1, wc = wid & 1;

    f32x4 acc[2][4];
#pragma unroll
    for (int i = 0; i < 2; ++i)
#pragma unroll
        for (int j = 0; j < 4; ++j) acc[i][j] = (f32x4){0.f, 0.f, 0.f, 0.f};

#define STAGE(BUF, TC) do {                                                   \
    const int kb_ = (TC) * 64;                                                \
    _Pragma("unroll")                                                         \
    for (int it = 0; it < 6; ++it) {                                          \
        int c = wid * 6 + it;                                                 \
        if (c < 8) {                                                          \
            int mt = c >> 1, kt2 = c & 1;                                     \
            int row = row0 + mt * 16 + lrow;                                  \
            int kk = kt2 * 32 + lk8 * 8;                                      \
            const unsigned short* gp = ((TC) < 8)                             \
                ? accb + (size_t)row * KBIG + kb_ + kk                        \
                : xh + (size_t)row * FDIM + (kb_ - KBIG) + kk;                \
            async_copy16(gp, &sA[BUF][c * 512]);                              \
        } else {                                                              \
            int d = c - 8; int nt = d >> 1, kt2 = d & 1;                      \
            const unsigned short* gp =                                        \
                wt + (size_t)(nt * 16 + lrow) * KTOT + kb_ + kt2 * 32 + lk8 * 8; \
            async_copy16(gp, &sB[BUF][d * 512]);                              \
        }                                                                     \
    } } while (0)

#define COMPUTE(BUF) do {                                                     \
    _Pragma("unroll")                                                         \
    for (int kt = 0; kt < 2; ++kt) {                                          \
        s16x8 a[2], b[4];                                                     \
        _Pragma("unroll")                                                     \
        for (int i = 0; i < 2; ++i)                                           \
            a[i] = *(const s16x8*)&sA[BUF][((wr * 2 + i) * 2 + kt) * 512 + lane * 8]; \
        _Pragma("unroll")                                                     \
        for (int j = 0; j < 4; ++j)                                           \
            b[j] = *(const s16x8*)&sB[BUF][((wc * 4 + j) * 2 + kt) * 512 + lane * 8]; \
        _Pragma("unroll")                                                     \
        for (int i = 0; i < 2; ++i)                                           \
            _Pragma("unroll")                                                 \
            for (int j = 0; j < 4; ++j)                                       \
                acc[i][j] = __builtin_amdgcn_mfma_f32_16x16x32_bf16(a[i], b[j], acc[i][j], 0, 0, 0); \
    } } while (0)

    STAGE(0, 0);
    for (int t = 0; t < 9; ++t) {
        STAGE((t + 1) & 1, t + 1);
        asm volatile("s_waitcnt vmcnt(6)" ::: "memory");  // chunk t arrived, t+1 in flight
        __builtin_amdgcn_s_barrier();
        COMPUTE(t & 1);
        __builtin_amdgcn_s_barrier();                     // all reads of buf t&1 done
    }
    asm volatile("s_waitcnt vmcnt(0)" ::: "memory");
    __builtin_amdgcn_s_barrier();
    COMPUTE(1);                                           // chunk 9

#undef STAGE
#undef COMPUTE

    // epilogue: C/D layout col=lane&15, row=(lane>>4)*4+reg  [m89-verified]
    float bb[4];
#pragma unroll
    for (int j = 0; j < 4; ++j) bb[j] = bias[wc * 64 + j * 16 + lrow];
#pragma unroll
    for (int i = 0; i < 2; ++i)
#pragma unroll
        for (int j = 0; j < 4; ++j)
#pragma unroll
            for (int q = 0; q < 4; ++q) {
                int row = row0 + wr * 32 + i * 16 + lk8 * 4 + q;
                int col = wc * 64 + j * 16 + lrow;
                float v = acc[i][j][q] + bb[j];
                if (RELU) v = fmaxf(v, 0.f);
                if (OUT_BF16) hout[(size_t)row * FDIM + col] = f2bf(v);
                else          fout[(size_t)row * FDIM + col] = v;
            }
}

extern "C" void kernel_launch(void* const* d_in, const int* in_sizes, int n_in,
                              void* d_out, int out_size, void* d_ws, size_t ws_size,
                              hipStream_t stream) {
    const float* x     = (const float*)d_in[0];
    const float* w1    = (const float*)d_in[1];
    const float* root1 = (const float*)d_in[2];
    const float* b1    = (const float*)d_in[3];
    const float* w2    = (const float*)d_in[4];
    const float* root2 = (const float*)d_in[5];
    const float* b2    = (const float*)d_in[6];
    const int*   ei    = (const int*)d_in[7];   // [2, E]
    const int*   et    = (const int*)d_in[8];   // [E]
    float* out = (float*)d_out;

    const int* srcv = ei;
    const int* dstv = ei + E_EDGES;

    // ---- workspace layout ----
    size_t io = 0;
    int* cnt_i  = (int*)d_ws + io;  io += NSEG;
    int* offs   = (int*)d_ws + io;  io += NSEG + 1;
    int* cursor = (int*)d_ws + io;  io += NSEG;
    int* csr    = (int*)d_ws + io;  io += CSR_PAD;
    int* bsum   = (int*)d_ws + io;  io += SCAN_BLOCKS;
    int* bpre   = (int*)d_ws + io;  io += SCAN_BLOCKS;
    io = (io + 63) & ~(size_t)63;                       // 256B-align
    unsigned short* us  = (unsigned short*)((int*)d_ws + io);
    size_t uo = 0;
    unsigned short* xb   = us + uo;  uo += (size_t)(N_NODES + 1) * FDIM;  // +dummy row
    unsigned short* wt1  = us + uo;  uo += (size_t)FDIM * KTOT;
    unsigned short* wt2  = us + uo;  uo += (size_t)FDIM * KTOT;
    unsigned short* h    = us + uo;  uo += (size_t)(N_NODES + 1) * FDIM;  // +dummy row
    unsigned short* accb = us + uo;  uo += (size_t)NSEG * FDIM;

    const int eb = (E_EDGES + 255) / 256;      // 2500

    // ---- setup (zero cnt + converts + csr dummy-fill + zero dummy rows) ----
    setup_kernel<<<SB_CNT + SB_CX + SB_CW + SB_CF + 1, 256, 0, stream>>>(
        x, w1, root1, w2, root2, cnt_i, xb, wt1, wt2, csr, h);

    // ---- build CSR once (reused by both layers) ----
    hist_kernel<<<eb, 256, 0, stream>>>(dstv, et, cnt_i);
    scan_part<<<SCAN_BLOCKS, 256, 0, stream>>>(cnt_i, bsum);
    scan_mid<<<1, 1024, 0, stream>>>(bsum, bpre);
    scan_final<<<SCAN_BLOCKS, 256, 0, stream>>>(cnt_i, bpre, offs, cursor);
    build_kernel<<<eb, 256, 0, stream>>>(srcv, dstv, et, cursor, csr);

    // ---- layer 1: agg(x) -> accb; h = relu([accb|x] @ Wt1 + b1) ----
    agg_kernel<<<N_NODES / 4, 256, 0, stream>>>(xb, offs, cnt_i, csr, accb);
    gemm_k640<1, 1><<<N_NODES / 64, 256, 0, stream>>>(accb, xb, wt1, b1, h, nullptr);

    // ---- layer 2: agg(h) -> accb; out = [accb|h] @ Wt2 + b2 ----
    agg_kernel<<<N_NODES / 4, 256, 0, stream>>>(h, offs, cnt_i, csr, accb);
    gemm_k640<0, 0><<<N_NODES / 64, 256, 0, stream>>>(accb, h, wt2, b2, nullptr, out);
}